// Round 1
// baseline (447.864 us; speedup 1.0000x reference)
//
#include <hip/hip_runtime.h>

typedef unsigned short u16;
typedef unsigned int u32;
typedef __bf16 bf16x8 __attribute__((ext_vector_type(8)));
typedef float f32x4 __attribute__((ext_vector_type(4)));
typedef u16 u16x4 __attribute__((ext_vector_type(4)));
typedef __attribute__((address_space(1))) void* as1_t;
typedef __attribute__((address_space(3))) void* as3_t;

#define LOG2E 1.4426950408889634f
#define MFMA(a,b,c) __builtin_amdgcn_mfma_f32_16x16x32_bf16(a,b,c,0,0,0)

__device__ __forceinline__ u16 f2bf(float f){
  u32 u = __float_as_uint(f);
  return (u16)((u + 0x7FFFu + ((u >> 16) & 1u)) >> 16);
}

__device__ __forceinline__ void gld16(const u16* gp, u16* lp){
  // 16B per lane, LDS dest = wave-uniform base + lane*16
  __builtin_amdgcn_global_load_lds((as1_t)(u16*)gp, (as3_t)lp, 16, 0, 0);
}

// ---------------- cast f32 -> bf16 ----------------
__global__ void cast_bf16_kernel(const float* __restrict__ in, u16* __restrict__ out, int n){
  int idx = (blockIdx.x*256 + threadIdx.x)*4;
  if(idx < n){
    float4 v = *(const float4*)(in + idx);
    u16x4 o = { f2bf(v.x), f2bf(v.y), f2bf(v.z), f2bf(v.w) };
    *(u16x4*)(out + idx) = o;
  }
}

// ---------------- W [1024x1024] f32 -> WT [n][k] bf16 ----------------
__global__ void transpose_w_kernel(const float* __restrict__ W, u16* __restrict__ WT){
  __shared__ u16 t[64][65];
  int bn = blockIdx.x*64, bk = blockIdx.y*64;
  int c = threadIdx.x & 63, r0 = threadIdx.x >> 6;
  #pragma unroll
  for(int j=0;j<64;j+=4){
    int r = r0 + j;
    t[r][c] = f2bf(W[(bk + r)*1024 + bn + c]);
  }
  __syncthreads();
  #pragma unroll
  for(int j=0;j<64;j+=4){
    int r = r0 + j;
    WT[(bn + r)*1024 + bk + c] = t[c][r];
  }
}

// ---------------- per-head transpose [BH][1024][64] -> [BH][64][1024] ----------------
__global__ void transpose_head_kernel(const u16* __restrict__ in, u16* __restrict__ out){
  __shared__ u16 t[64][65];
  int bh = blockIdx.y; int s0 = blockIdx.x*64;
  int c = threadIdx.x & 63, r0 = threadIdx.x >> 6;
  #pragma unroll
  for(int j=0;j<64;j+=4){
    int r = r0 + j;
    t[r][c] = in[(size_t)bh*65536 + (size_t)(s0 + r)*64 + c];
  }
  __syncthreads();
  #pragma unroll
  for(int j=0;j<64;j+=4){
    int d = r0 + j;
    out[(size_t)bh*65536 + (size_t)d*1024 + s0 + c] = t[c][d];
  }
}

// ---------------- GEMM: C[M x 1024] = A[M x 1024] * Bt[n][k], bf16 in, 128x128 tile ----------------
// mode 0: store bf16 head-split [b][h][s][d];  mode 1: store f32 row-major
__global__ __launch_bounds__(256, 2)
void gemm_bt_kernel(const u16* __restrict__ A, const u16* __restrict__ Bt,
                    u16* __restrict__ Cbf, float* __restrict__ Cf, int mode)
{
  __shared__ u16 lds[8192];        // A: [c4][128][8], B: [c4][128][8]
  u16* Al = lds; u16* Bl = lds + 4096;
  const int tid = threadIdx.x, w = tid >> 6, lane = tid & 63;
  const int quad = lane >> 4, cl = lane & 15;
  const int bm = blockIdx.y*128, bn = blockIdx.x*128;
  const int wm = (w >> 1)*64, wn = (w & 1)*64;
  const int K = 1024;
  f32x4 acc[4][4];
  #pragma unroll
  for(int a=0;a<4;a++)
    #pragma unroll
    for(int b=0;b<4;b++){ f32x4 z = {0.f,0.f,0.f,0.f}; acc[a][b] = z; }

  for(int k0=0;k0<K;k0+=32){
    __syncthreads();
    #pragma unroll
    for(int i=0;i<2;i++){
      int slot = (w*2+i)*64 + lane;
      int c = slot >> 7, r = slot & 127;
      gld16(A  + (size_t)(bm + r)*K + k0 + c*8, Al + (w*2+i)*512);
      gld16(Bt + (size_t)(bn + r)*K + k0 + c*8, Bl + (w*2+i)*512);
    }
    __syncthreads();
    bf16x8 af[4], bfv[4];
    #pragma unroll
    for(int mt=0;mt<4;mt++) af[mt]  = *(const bf16x8*)(Al + (quad*128 + wm + mt*16 + cl)*8);
    #pragma unroll
    for(int nt=0;nt<4;nt++) bfv[nt] = *(const bf16x8*)(Bl + (quad*128 + wn + nt*16 + cl)*8);
    #pragma unroll
    for(int mt=0;mt<4;mt++)
      #pragma unroll
      for(int nt=0;nt<4;nt++)
        acc[mt][nt] = MFMA(af[mt], bfv[nt], acc[mt][nt]);
  }
  #pragma unroll
  for(int mt=0;mt<4;mt++)
    #pragma unroll
    for(int nt=0;nt<4;nt++)
      #pragma unroll
      for(int i=0;i<4;i++){
        int m = bm + wm + mt*16 + quad*4 + i;
        int n = bn + wn + nt*16 + cl;
        float v = acc[mt][nt][i];
        if(mode == 0){
          int b = m >> 10, s = m & 1023, h = n >> 6, d = n & 63;
          Cbf[(((size_t)(b*16 + h)*1024 + s) << 6) + d] = f2bf(v);
        } else {
          Cf[(size_t)m*1024 + n] = v;
        }
      }
}

// ---------------- attention (vis): per (b,h,q-tile), two-pass softmax + P@V^T ----------------
__global__ __launch_bounds__(256, 2)
void attn_vis_kernel(const u16* __restrict__ Q, const u16* __restrict__ Kc,
                     const u16* __restrict__ Vt, u16* __restrict__ visA,
                     float* __restrict__ m_g, float* __restrict__ rl_g)
{
  __shared__ u16 lds[33792];
  u16* Pl = lds;             // 128*136 bf16 (Q tile staged in first 8192 initially)
  u16* Kl = lds + 17408;     // [c8][128][8]
  u16* Vl = lds + 25600;     // [kc16][64][8]
  const int tid = threadIdx.x, w = tid>>6, lane = tid&63;
  const int quad = lane>>4, cl = lane&15;
  const int bh = blockIdx.y, q0 = blockIdx.x*128;
  const u16* Qh  = Q  + (size_t)bh*65536;
  const u16* Kh  = Kc + (size_t)bh*65536;
  const u16* Vth = Vt + (size_t)bh*65536;

  #pragma unroll
  for(int i=0;i<4;i++){
    int slot = (w*4+i)*64 + lane;
    int c = slot >> 7, r = slot & 127;
    gld16(Qh + (size_t)(q0 + r)*64 + c*8, Pl + (w*4+i)*512);
  }
  __syncthreads();
  bf16x8 qf[2][2];
  #pragma unroll
  for(int mt=0;mt<2;mt++)
    #pragma unroll
    for(int kk=0;kk<2;kk++)
      qf[mt][kk] = *(const bf16x8*)(Pl + ((kk*4+quad)*128 + w*32 + mt*16 + cl)*8);

  float mrun[2][4], lrun[2][4];
  #pragma unroll
  for(int mt=0;mt<2;mt++)
    #pragma unroll
    for(int i=0;i<4;i++){ mrun[mt][i] = -1e30f; lrun[mt][i] = 0.f; }

  // ---- pass 1: row max + sumexp ----
  for(int kt=0;kt<8;kt++){
    __syncthreads();
    #pragma unroll
    for(int i=0;i<4;i++){
      int slot = (w*4+i)*64 + lane;
      int c = slot >> 7, r = slot & 127;
      gld16(Kh + (size_t)(kt*128 + r)*64 + c*8, Kl + (w*4+i)*512);
    }
    __syncthreads();
    f32x4 s[2][8];
    #pragma unroll
    for(int mt=0;mt<2;mt++)
      #pragma unroll
      for(int nt=0;nt<8;nt++){ f32x4 z = {0.f,0.f,0.f,0.f}; s[mt][nt] = z; }
    #pragma unroll
    for(int nt=0;nt<8;nt++)
      #pragma unroll
      for(int kk=0;kk<2;kk++){
        bf16x8 kf = *(const bf16x8*)(Kl + ((kk*4+quad)*128 + nt*16 + cl)*8);
        s[0][nt] = MFMA(qf[0][kk], kf, s[0][nt]);
        s[1][nt] = MFMA(qf[1][kk], kf, s[1][nt]);
      }
    #pragma unroll
    for(int mt=0;mt<2;mt++)
      #pragma unroll
      for(int i=0;i<4;i++){
        float mx = s[mt][0][i];
        #pragma unroll
        for(int nt=1;nt<8;nt++) mx = fmaxf(mx, s[mt][nt][i]);
        #pragma unroll
        for(int off=1;off<16;off<<=1) mx = fmaxf(mx, __shfl_xor(mx, off, 64));
        float mo = mrun[mt][i];
        float mn = fmaxf(mo, mx);
        float sum = 0.f;
        #pragma unroll
        for(int nt=0;nt<8;nt++) sum += exp2f((s[mt][nt][i]-mn)*LOG2E);
        #pragma unroll
        for(int off=1;off<16;off<<=1) sum += __shfl_xor(sum, off, 64);
        lrun[mt][i] = lrun[mt][i]*exp2f((mo-mn)*LOG2E) + sum;
        mrun[mt][i] = mn;
      }
  }
  float rl[2][4];
  #pragma unroll
  for(int mt=0;mt<2;mt++)
    #pragma unroll
    for(int i=0;i<4;i++) rl[mt][i] = 1.f/lrun[mt][i];
  if(cl == 0){
    #pragma unroll
    for(int mt=0;mt<2;mt++)
      #pragma unroll
      for(int i=0;i<4;i++){
        int r = w*32 + mt*16 + quad*4 + i;
        m_g [bh*1024 + q0 + r] = mrun[mt][i];
        rl_g[bh*1024 + q0 + r] = rl[mt][i];
      }
  }

  // ---- pass 2: P = softmax(S), O += P @ V^T ----
  f32x4 oacc[2][4];
  #pragma unroll
  for(int mt=0;mt<2;mt++)
    #pragma unroll
    for(int dt=0;dt<4;dt++){ f32x4 z = {0.f,0.f,0.f,0.f}; oacc[mt][dt] = z; }

  for(int kt=0;kt<8;kt++){
    __syncthreads();
    #pragma unroll
    for(int i=0;i<4;i++){
      int slot = (w*4+i)*64 + lane;
      int c = slot >> 7, r = slot & 127;
      gld16(Kh  + (size_t)(kt*128 + r)*64 + c*8, Kl + (w*4+i)*512);
      gld16(Vth + (size_t)lane*1024 + kt*128 + (w*4+i)*8, Vl + (w*4+i)*512);
    }
    __syncthreads();
    f32x4 s[2][8];
    #pragma unroll
    for(int mt=0;mt<2;mt++)
      #pragma unroll
      for(int nt=0;nt<8;nt++){ f32x4 z = {0.f,0.f,0.f,0.f}; s[mt][nt] = z; }
    #pragma unroll
    for(int nt=0;nt<8;nt++)
      #pragma unroll
      for(int kk=0;kk<2;kk++){
        bf16x8 kf = *(const bf16x8*)(Kl + ((kk*4+quad)*128 + nt*16 + cl)*8);
        s[0][nt] = MFMA(qf[0][kk], kf, s[0][nt]);
        s[1][nt] = MFMA(qf[1][kk], kf, s[1][nt]);
      }
    #pragma unroll
    for(int mt=0;mt<2;mt++)
      #pragma unroll
      for(int nt=0;nt<8;nt++)
        #pragma unroll
        for(int i=0;i<4;i++){
          float p = exp2f((s[mt][nt][i]-mrun[mt][i])*LOG2E)*rl[mt][i];
          int qrow = w*32 + mt*16 + quad*4 + i;
          int k = nt*16 + cl;
          Pl[qrow*136 + k] = f2bf(p);   // own-wave rows only
        }
    #pragma unroll
    for(int kk=0;kk<4;kk++){
      bf16x8 pa0 = *(const bf16x8*)(Pl + (w*32 + cl)*136 + kk*32 + quad*8);
      bf16x8 pa1 = *(const bf16x8*)(Pl + (w*32 + 16 + cl)*136 + kk*32 + quad*8);
      #pragma unroll
      for(int dt=0;dt<4;dt++){
        bf16x8 vb = *(const bf16x8*)(Vl + ((kk*4+quad)*64 + dt*16 + cl)*8);
        oacc[0][dt] = MFMA(pa0, vb, oacc[0][dt]);
        oacc[1][dt] = MFMA(pa1, vb, oacc[1][dt]);
      }
    }
  }
  const int b = bh >> 4, h = bh & 15;
  #pragma unroll
  for(int mt=0;mt<2;mt++)
    #pragma unroll
    for(int dt=0;dt<4;dt++)
      #pragma unroll
      for(int i=0;i<4;i++){
        int r = w*32 + mt*16 + quad*4 + i;
        visA[(size_t)(b*1024 + q0 + r)*1024 + h*64 + dt*16 + cl] = f2bf(oacc[mt][dt][i]);
      }
}

// ---------------- attention (txt): per (b,h,k-tile), S^T tiles + P^T @ V2 ----------------
__global__ __launch_bounds__(256, 2)
void attn_txt_kernel(const u16* __restrict__ Kc, const u16* __restrict__ Q,
                     const u16* __restrict__ V2t, const float* __restrict__ m_g,
                     const float* __restrict__ rl_g, u16* __restrict__ txtA)
{
  __shared__ u16 lds[33792];
  u16* Pl = lds;             // 128*136 (K tile staged in first 8192 initially)
  u16* Ql = lds + 17408;
  u16* Vl = lds + 25600;
  const int tid = threadIdx.x, w = tid>>6, lane = tid&63;
  const int quad = lane>>4, cl = lane&15;
  const int bh = blockIdx.y, k0 = blockIdx.x*128;
  const u16* Kh  = Kc  + (size_t)bh*65536;
  const u16* Qh  = Q   + (size_t)bh*65536;
  const u16* Vth = V2t + (size_t)bh*65536;

  #pragma unroll
  for(int i=0;i<4;i++){
    int slot = (w*4+i)*64 + lane;
    int c = slot >> 7, r = slot & 127;
    gld16(Kh + (size_t)(k0 + r)*64 + c*8, Pl + (w*4+i)*512);
  }
  __syncthreads();
  bf16x8 kf[2][2];
  #pragma unroll
  for(int mt=0;mt<2;mt++)
    #pragma unroll
    for(int kk=0;kk<2;kk++)
      kf[mt][kk] = *(const bf16x8*)(Pl + ((kk*4+quad)*128 + w*32 + mt*16 + cl)*8);

  f32x4 oacc[2][4];
  #pragma unroll
  for(int mt=0;mt<2;mt++)
    #pragma unroll
    for(int dt=0;dt<4;dt++){ f32x4 z = {0.f,0.f,0.f,0.f}; oacc[mt][dt] = z; }

  for(int qt=0;qt<8;qt++){
    __syncthreads();
    #pragma unroll
    for(int i=0;i<4;i++){
      int slot = (w*4+i)*64 + lane;
      int c = slot >> 7, r = slot & 127;
      gld16(Qh  + (size_t)(qt*128 + r)*64 + c*8, Ql + (w*4+i)*512);
      gld16(Vth + (size_t)lane*1024 + qt*128 + (w*4+i)*8, Vl + (w*4+i)*512);
    }
    __syncthreads();
    f32x4 s[2][8];
    #pragma unroll
    for(int mt=0;mt<2;mt++)
      #pragma unroll
      for(int nt=0;nt<8;nt++){ f32x4 z = {0.f,0.f,0.f,0.f}; s[mt][nt] = z; }
    #pragma unroll
    for(int nt=0;nt<8;nt++)
      #pragma unroll
      for(int kk=0;kk<2;kk++){
        bf16x8 qb = *(const bf16x8*)(Ql + ((kk*4+quad)*128 + nt*16 + cl)*8);
        s[0][nt] = MFMA(kf[0][kk], qb, s[0][nt]);
        s[1][nt] = MFMA(kf[1][kk], qb, s[1][nt]);
      }
    float pm[8], pr[8];
    #pragma unroll
    for(int nt=0;nt<8;nt++){
      int qq = bh*1024 + qt*128 + nt*16 + cl;
      pm[nt] = m_g[qq];
      pr[nt] = rl_g[qq];
    }
    #pragma unroll
    for(int mt=0;mt<2;mt++)
      #pragma unroll
      for(int nt=0;nt<8;nt++)
        #pragma unroll
        for(int i=0;i<4;i++){
          float p = exp2f((s[mt][nt][i]-pm[nt])*LOG2E)*pr[nt];
          int kr = w*32 + mt*16 + quad*4 + i;
          int qc = nt*16 + cl;
          Pl[kr*136 + qc] = f2bf(p);   // own-wave rows only
        }
    #pragma unroll
    for(int kk=0;kk<4;kk++){
      bf16x8 pa0 = *(const bf16x8*)(Pl + (w*32 + cl)*136 + kk*32 + quad*8);
      bf16x8 pa1 = *(const bf16x8*)(Pl + (w*32 + 16 + cl)*136 + kk*32 + quad*8);
      #pragma unroll
      for(int dt=0;dt<4;dt++){
        bf16x8 vb = *(const bf16x8*)(Vl + ((kk*4+quad)*64 + dt*16 + cl)*8);
        oacc[0][dt] = MFMA(pa0, vb, oacc[0][dt]);
        oacc[1][dt] = MFMA(pa1, vb, oacc[1][dt]);
      }
    }
  }
  const int b = bh >> 4, h = bh & 15;
  #pragma unroll
  for(int mt=0;mt<2;mt++)
    #pragma unroll
    for(int dt=0;dt<4;dt++)
      #pragma unroll
      for(int i=0;i<4;i++){
        int r = w*32 + mt*16 + quad*4 + i;
        txtA[(size_t)(b*1024 + k0 + r)*1024 + h*64 + dt*16 + cl] = f2bf(oacc[mt][dt][i]);
      }
}

extern "C" void kernel_launch(void* const* d_in, const int* in_sizes, int n_in,
                              void* d_out, int out_size, void* d_ws, size_t ws_size,
                              hipStream_t stream)
{
  const float* vis = (const float*)d_in[0];
  const float* txt = (const float*)d_in[1];
  const float* Wq  = (const float*)d_in[2];
  const float* Wk  = (const float*)d_in[3];
  const float* Wv  = (const float*)d_in[4];
  const float* Wo  = (const float*)d_in[5];
  float* out = (float*)d_out;

  char* ws = (char*)d_ws;
  const size_t MB = 1u << 20;
  u16* vis16 = (u16*)(ws + 0);          // reused as Vt after projections
  u16* txt16 = (u16*)(ws + 8*MB);       // reused as V2t
  u16* WqT   = (u16*)(ws + 16*MB);
  u16* WkT   = (u16*)(ws + 18*MB);
  u16* WvT   = (u16*)(ws + 20*MB);
  u16* WoT   = (u16*)(ws + 22*MB);
  u16* Qb    = (u16*)(ws + 24*MB);
  u16* Kb    = (u16*)(ws + 32*MB);
  u16* Vb    = (u16*)(ws + 40*MB);      // reused as visA
  u16* V2b   = (u16*)(ws + 48*MB);      // reused as txtA
  float* m_g  = (float*)(ws + 56*MB);
  float* rl_g = (float*)(ws + 56*MB + 262144);
  u16* Vt = vis16; u16* V2t = txt16;
  u16* visA = Vb;  u16* txtA = V2b;

  const int NELT = 4*1024*1024;
  cast_bf16_kernel<<<NELT/1024, 256, 0, stream>>>(vis, vis16, NELT);
  cast_bf16_kernel<<<NELT/1024, 256, 0, stream>>>(txt, txt16, NELT);
  transpose_w_kernel<<<dim3(16,16), 256, 0, stream>>>(Wq, WqT);
  transpose_w_kernel<<<dim3(16,16), 256, 0, stream>>>(Wk, WkT);
  transpose_w_kernel<<<dim3(16,16), 256, 0, stream>>>(Wv, WvT);
  transpose_w_kernel<<<dim3(16,16), 256, 0, stream>>>(Wo, WoT);
  // projections -> head-split bf16 [b][h][s][64]
  gemm_bt_kernel<<<dim3(8,32), 256, 0, stream>>>(vis16, WqT, Qb,  nullptr, 0);
  gemm_bt_kernel<<<dim3(8,32), 256, 0, stream>>>(txt16, WkT, Kb,  nullptr, 0);
  gemm_bt_kernel<<<dim3(8,32), 256, 0, stream>>>(txt16, WvT, Vb,  nullptr, 0);
  gemm_bt_kernel<<<dim3(8,32), 256, 0, stream>>>(vis16, WvT, V2b, nullptr, 0);
  // per-head transposes for PV operands
  transpose_head_kernel<<<dim3(16,64), 256, 0, stream>>>(Vb,  Vt);
  transpose_head_kernel<<<dim3(16,64), 256, 0, stream>>>(V2b, V2t);
  // attention
  attn_vis_kernel<<<dim3(8,64), 256, 0, stream>>>(Qb, Kb, Vt, visA, m_g, rl_g);
  attn_txt_kernel<<<dim3(8,64), 256, 0, stream>>>(Kb, Qb, V2t, m_g, rl_g, txtA);
  // output projections -> f32
  gemm_bt_kernel<<<dim3(8,32), 256, 0, stream>>>(visA, WoT, nullptr, out, 1);
  gemm_bt_kernel<<<dim3(8,32), 256, 0, stream>>>(txtA, WoT, nullptr, out + NELT, 1);
}

// Round 2
// 439.113 us; speedup vs baseline: 1.0199x; 1.0199x over previous
//
#include <hip/hip_runtime.h>

typedef unsigned short u16;
typedef unsigned int u32;
typedef __bf16 bf16x8 __attribute__((ext_vector_type(8)));
typedef float f32x4 __attribute__((ext_vector_type(4)));
typedef u16 u16x4 __attribute__((ext_vector_type(4)));
typedef __attribute__((address_space(1))) void* as1_t;
typedef __attribute__((address_space(3))) void* as3_t;

#define LOG2E 1.4426950408889634f
#define MFMA(a,b,c) __builtin_amdgcn_mfma_f32_16x16x32_bf16(a,b,c,0,0,0)

__device__ __forceinline__ u16 f2bf(float f){
  u32 u = __float_as_uint(f);
  return (u16)((u + 0x7FFFu + ((u >> 16) & 1u)) >> 16);
}

__device__ __forceinline__ void gld16(const u16* gp, u16* lp){
  // 16B per lane, LDS dest = wave-uniform base + lane*16
  __builtin_amdgcn_global_load_lds((as1_t)(u16*)gp, (as3_t)lp, 16, 0, 0);
}

// ---------------- cast f32 -> bf16 ----------------
__global__ void cast_bf16_kernel(const float* __restrict__ in, u16* __restrict__ out, int n){
  int idx = (blockIdx.x*256 + threadIdx.x)*4;
  if(idx < n){
    float4 v = *(const float4*)(in + idx);
    u16x4 o = { f2bf(v.x), f2bf(v.y), f2bf(v.z), f2bf(v.w) };
    *(u16x4*)(out + idx) = o;
  }
}

// ---------------- W [1024x1024] f32 -> WT [n][k] bf16 ----------------
__global__ void transpose_w_kernel(const float* __restrict__ W, u16* __restrict__ WT){
  __shared__ u16 t[64][65];
  int bn = blockIdx.x*64, bk = blockIdx.y*64;
  int c = threadIdx.x & 63, r0 = threadIdx.x >> 6;
  #pragma unroll
  for(int j=0;j<64;j+=4){
    int r = r0 + j;
    t[r][c] = f2bf(W[(bk + r)*1024 + bn + c]);
  }
  __syncthreads();
  #pragma unroll
  for(int j=0;j<64;j+=4){
    int r = r0 + j;
    WT[(bn + r)*1024 + bk + c] = t[c][r];
  }
}

// ---------------- per-head transpose [BH][1024][64] -> [BH][64][1024] ----------------
__global__ void transpose_head_kernel(const u16* __restrict__ in, u16* __restrict__ out){
  __shared__ u16 t[64][65];
  int bh = blockIdx.y; int s0 = blockIdx.x*64;
  int c = threadIdx.x & 63, r0 = threadIdx.x >> 6;
  #pragma unroll
  for(int j=0;j<64;j+=4){
    int r = r0 + j;
    t[r][c] = in[(size_t)bh*65536 + (size_t)(s0 + r)*64 + c];
  }
  __syncthreads();
  #pragma unroll
  for(int j=0;j<64;j+=4){
    int d = r0 + j;
    out[(size_t)bh*65536 + (size_t)d*1024 + s0 + c] = t[c][d];
  }
}

// ---------------- GEMM: C[M x 1024] = A[M x 1024] * Bt[n][k], bf16 in, 128x128 tile ----------------
// mode 0: store bf16 head-split [b][h][s][d];  mode 1: store f32 row-major
__global__ __launch_bounds__(256, 2)
void gemm_bt_kernel(const u16* __restrict__ A, const u16* __restrict__ Bt,
                    u16* __restrict__ Cbf, float* __restrict__ Cf, int mode)
{
  __shared__ u16 lds[8192];        // A: [c4][128][8], B: [c4][128][8]
  u16* Al = lds; u16* Bl = lds + 4096;
  const int tid = threadIdx.x, w = tid >> 6, lane = tid & 63;
  const int quad = lane >> 4, cl = lane & 15;
  const int bm = blockIdx.y*128, bn = blockIdx.x*128;
  const int wm = (w >> 1)*64, wn = (w & 1)*64;
  const int K = 1024;
  f32x4 acc[4][4];
  #pragma unroll
  for(int a=0;a<4;a++)
    #pragma unroll
    for(int b=0;b<4;b++){ f32x4 z = {0.f,0.f,0.f,0.f}; acc[a][b] = z; }

  for(int k0=0;k0<K;k0+=32){
    __syncthreads();
    #pragma unroll
    for(int i=0;i<2;i++){
      int slot = (w*2+i)*64 + lane;
      int c = slot >> 7, r = slot & 127;
      gld16(A  + (size_t)(bm + r)*K + k0 + c*8, Al + (w*2+i)*512);
      gld16(Bt + (size_t)(bn + r)*K + k0 + c*8, Bl + (w*2+i)*512);
    }
    __syncthreads();
    bf16x8 af[4], bfv[4];
    #pragma unroll
    for(int mt=0;mt<4;mt++) af[mt]  = *(const bf16x8*)(Al + (quad*128 + wm + mt*16 + cl)*8);
    #pragma unroll
    for(int nt=0;nt<4;nt++) bfv[nt] = *(const bf16x8*)(Bl + (quad*128 + wn + nt*16 + cl)*8);
    #pragma unroll
    for(int mt=0;mt<4;mt++)
      #pragma unroll
      for(int nt=0;nt<4;nt++)
        acc[mt][nt] = MFMA(af[mt], bfv[nt], acc[mt][nt]);
  }
  #pragma unroll
  for(int mt=0;mt<4;mt++)
    #pragma unroll
    for(int nt=0;nt<4;nt++)
      #pragma unroll
      for(int i=0;i<4;i++){
        int m = bm + wm + mt*16 + quad*4 + i;
        int n = bn + wn + nt*16 + cl;
        float v = acc[mt][nt][i];
        if(mode == 0){
          int b = m >> 10, s = m & 1023, h = n >> 6, d = n & 63;
          Cbf[(((size_t)(b*16 + h)*1024 + s) << 6) + d] = f2bf(v);
        } else {
          Cf[(size_t)m*1024 + n] = v;
        }
      }
}

// ---------------- attention (vis): flash single-pass, 128 q-rows/block, 64-k tiles ----------------
__global__ __launch_bounds__(256, 4)
void attn_vis_kernel(const u16* __restrict__ Q, const u16* __restrict__ Kc,
                     const u16* __restrict__ Vt, u16* __restrict__ visA,
                     float* __restrict__ m_g, float* __restrict__ rl_g)
{
  __shared__ u16 lds[17408];   // 34816 B -> 4 blocks/CU
  u16* Pl = lds;               // P: 128 x 72 (9216 u16); Q staged here first (8192 u16)
  u16* Kl = lds + 9216;        // [c8][64][8]  = 4096 u16
  u16* Vl = lds + 13312;       // [c8][64][8]  = 4096 u16
  const int tid = threadIdx.x, w = tid>>6, lane = tid&63;
  const int quad = lane>>4, cl = lane&15;
  const int bh = blockIdx.y, q0 = blockIdx.x*128;
  const u16* Qh  = Q  + (size_t)bh*65536;
  const u16* Kh  = Kc + (size_t)bh*65536;
  const u16* Vth = Vt + (size_t)bh*65536;

  // stage Q tile (128x64) into Pl, read persistent A-fragments
  #pragma unroll
  for(int i=0;i<4;i++){
    int slot = (w*4+i)*64 + lane;
    int c = slot >> 7, r = slot & 127;
    gld16(Qh + (size_t)(q0 + r)*64 + c*8, Pl + slot*8);
  }
  __syncthreads();
  bf16x8 qf[2][2];
  #pragma unroll
  for(int mt=0;mt<2;mt++)
    #pragma unroll
    for(int kk=0;kk<2;kk++)
      qf[mt][kk] = *(const bf16x8*)(Pl + ((kk*4+quad)*128 + w*32 + mt*16 + cl)*8);

  float mrun[2][4], lrun[2][4];
  f32x4 oacc[2][4];
  #pragma unroll
  for(int mt=0;mt<2;mt++){
    #pragma unroll
    for(int i=0;i<4;i++){ mrun[mt][i] = -1e30f; lrun[mt][i] = 0.f; }
    #pragma unroll
    for(int dt=0;dt<4;dt++){ f32x4 z = {0.f,0.f,0.f,0.f}; oacc[mt][dt] = z; }
  }

  for(int kt=0;kt<16;kt++){
    __syncthreads();     // also drains qf reads on first iteration before P writes
    #pragma unroll
    for(int i=0;i<2;i++){
      int slot = (w*2+i)*64 + lane;
      int c = slot >> 6, r = slot & 63;
      gld16(Kh  + (size_t)(kt*64 + r)*64 + c*8, Kl + slot*8);
      gld16(Vth + (size_t)r*1024 + kt*64 + c*8, Vl + slot*8);
    }
    __syncthreads();
    // S = Q K^T  (64 cols this tile)
    f32x4 s[2][4];
    #pragma unroll
    for(int mt=0;mt<2;mt++)
      #pragma unroll
      for(int nt=0;nt<4;nt++){ f32x4 z = {0.f,0.f,0.f,0.f}; s[mt][nt] = z; }
    #pragma unroll
    for(int nt=0;nt<4;nt++)
      #pragma unroll
      for(int kk=0;kk<2;kk++){
        bf16x8 kfr = *(const bf16x8*)(Kl + ((kk*4+quad)*64 + nt*16 + cl)*8);
        s[0][nt] = MFMA(qf[0][kk], kfr, s[0][nt]);
        s[1][nt] = MFMA(qf[1][kk], kfr, s[1][nt]);
      }
    // online softmax + unnormalized P store
    #pragma unroll
    for(int mt=0;mt<2;mt++)
      #pragma unroll
      for(int i=0;i<4;i++){
        float mx = fmaxf(fmaxf(s[mt][0][i], s[mt][1][i]), fmaxf(s[mt][2][i], s[mt][3][i]));
        #pragma unroll
        for(int off=1;off<16;off<<=1) mx = fmaxf(mx, __shfl_xor(mx, off, 16));
        float mo = mrun[mt][i];
        float mn = fmaxf(mo, mx);
        float c2 = mn * LOG2E;
        float alpha = exp2f(fmaf(mo, LOG2E, -c2));
        float sum = 0.f;
        int row = w*32 + mt*16 + quad*4 + i;
        #pragma unroll
        for(int nt=0;nt<4;nt++){
          float p = exp2f(fmaf(s[mt][nt][i], LOG2E, -c2));
          sum += p;
          Pl[row*72 + nt*16 + cl] = f2bf(p);
        }
        #pragma unroll
        for(int off=1;off<16;off<<=1) sum += __shfl_xor(sum, off, 16);
        lrun[mt][i] = lrun[mt][i]*alpha + sum;
        mrun[mt][i] = mn;
        #pragma unroll
        for(int dt=0;dt<4;dt++) oacc[mt][dt][i] *= alpha;
      }
    // O += P @ V^T   (same-wave DS-pipe ordering: write then read own rows)
    #pragma unroll
    for(int kk=0;kk<2;kk++){
      bf16x8 pa0 = *(const bf16x8*)(Pl + (w*32 + cl)*72 + kk*32 + quad*8);
      bf16x8 pa1 = *(const bf16x8*)(Pl + (w*32 + 16 + cl)*72 + kk*32 + quad*8);
      #pragma unroll
      for(int dt=0;dt<4;dt++){
        bf16x8 vb = *(const bf16x8*)(Vl + ((kk*4+quad)*64 + dt*16 + cl)*8);
        oacc[0][dt] = MFMA(pa0, vb, oacc[0][dt]);
        oacc[1][dt] = MFMA(pa1, vb, oacc[1][dt]);
      }
    }
  }
  float rl[2][4];
  #pragma unroll
  for(int mt=0;mt<2;mt++)
    #pragma unroll
    for(int i=0;i<4;i++) rl[mt][i] = 1.f/lrun[mt][i];
  if(cl == 0){
    #pragma unroll
    for(int mt=0;mt<2;mt++)
      #pragma unroll
      for(int i=0;i<4;i++){
        int r = w*32 + mt*16 + quad*4 + i;
        m_g [bh*1024 + q0 + r] = mrun[mt][i];
        rl_g[bh*1024 + q0 + r] = rl[mt][i];
      }
  }
  const int b = bh >> 4, h = bh & 15;
  #pragma unroll
  for(int mt=0;mt<2;mt++)
    #pragma unroll
    for(int dt=0;dt<4;dt++)
      #pragma unroll
      for(int i=0;i<4;i++){
        int r = w*32 + mt*16 + quad*4 + i;
        visA[(size_t)(b*1024 + q0 + r)*1024 + h*64 + dt*16 + cl] = f2bf(oacc[mt][dt][i]*rl[mt][i]);
      }
}

// ---------------- attention (txt): per (b,h,k-tile), S^T tiles + P^T @ V2, 64-q tiles ----------------
__global__ __launch_bounds__(256, 4)
void attn_txt_kernel(const u16* __restrict__ Kc, const u16* __restrict__ Q,
                     const u16* __restrict__ V2t, const float* __restrict__ m_g,
                     const float* __restrict__ rl_g, u16* __restrict__ txtA)
{
  __shared__ u16 lds[17408];
  u16* Pl = lds;               // P^T: 128 x 72; K tile staged here first
  u16* Ql = lds + 9216;        // [c8][64][8]
  u16* Vl = lds + 13312;       // [c8][64][8]
  const int tid = threadIdx.x, w = tid>>6, lane = tid&63;
  const int quad = lane>>4, cl = lane&15;
  const int bh = blockIdx.y, k0 = blockIdx.x*128;
  const u16* Kh  = Kc  + (size_t)bh*65536;
  const u16* Qh  = Q   + (size_t)bh*65536;
  const u16* Vth = V2t + (size_t)bh*65536;

  #pragma unroll
  for(int i=0;i<4;i++){
    int slot = (w*4+i)*64 + lane;
    int c = slot >> 7, r = slot & 127;
    gld16(Kh + (size_t)(k0 + r)*64 + c*8, Pl + slot*8);
  }
  __syncthreads();
  bf16x8 kf[2][2];
  #pragma unroll
  for(int mt=0;mt<2;mt++)
    #pragma unroll
    for(int kk=0;kk<2;kk++)
      kf[mt][kk] = *(const bf16x8*)(Pl + ((kk*4+quad)*128 + w*32 + mt*16 + cl)*8);

  f32x4 oacc[2][4];
  #pragma unroll
  for(int mt=0;mt<2;mt++)
    #pragma unroll
    for(int dt=0;dt<4;dt++){ f32x4 z = {0.f,0.f,0.f,0.f}; oacc[mt][dt] = z; }

  for(int qt=0;qt<16;qt++){
    __syncthreads();
    #pragma unroll
    for(int i=0;i<2;i++){
      int slot = (w*2+i)*64 + lane;
      int c = slot >> 6, r = slot & 63;
      gld16(Qh  + (size_t)(qt*64 + r)*64 + c*8, Ql + slot*8);
      gld16(Vth + (size_t)r*1024 + qt*64 + c*8, Vl + slot*8);
    }
    __syncthreads();
    // S^T = K Q^T  (rows = k, cols = q)
    f32x4 s[2][4];
    #pragma unroll
    for(int mt=0;mt<2;mt++)
      #pragma unroll
      for(int nt=0;nt<4;nt++){ f32x4 z = {0.f,0.f,0.f,0.f}; s[mt][nt] = z; }
    #pragma unroll
    for(int nt=0;nt<4;nt++)
      #pragma unroll
      for(int kk=0;kk<2;kk++){
        bf16x8 qb = *(const bf16x8*)(Ql + ((kk*4+quad)*64 + nt*16 + cl)*8);
        s[0][nt] = MFMA(kf[0][kk], qb, s[0][nt]);
        s[1][nt] = MFMA(kf[1][kk], qb, s[1][nt]);
      }
    float pc[4], pr[4];
    #pragma unroll
    for(int nt=0;nt<4;nt++){
      int qq = bh*1024 + qt*64 + nt*16 + cl;
      pc[nt] = m_g[qq]*LOG2E;
      pr[nt] = rl_g[qq];
    }
    #pragma unroll
    for(int mt=0;mt<2;mt++)
      #pragma unroll
      for(int nt=0;nt<4;nt++)
        #pragma unroll
        for(int i=0;i<4;i++){
          float p = exp2f(fmaf(s[mt][nt][i], LOG2E, -pc[nt]))*pr[nt];
          Pl[(w*32 + mt*16 + quad*4 + i)*72 + nt*16 + cl] = f2bf(p);
        }
    #pragma unroll
    for(int kk=0;kk<2;kk++){
      bf16x8 pa0 = *(const bf16x8*)(Pl + (w*32 + cl)*72 + kk*32 + quad*8);
      bf16x8 pa1 = *(const bf16x8*)(Pl + (w*32 + 16 + cl)*72 + kk*32 + quad*8);
      #pragma unroll
      for(int dt=0;dt<4;dt++){
        bf16x8 vb = *(const bf16x8*)(Vl + ((kk*4+quad)*64 + dt*16 + cl)*8);
        oacc[0][dt] = MFMA(pa0, vb, oacc[0][dt]);
        oacc[1][dt] = MFMA(pa1, vb, oacc[1][dt]);
      }
    }
  }
  const int b = bh >> 4, h = bh & 15;
  #pragma unroll
  for(int mt=0;mt<2;mt++)
    #pragma unroll
    for(int dt=0;dt<4;dt++)
      #pragma unroll
      for(int i=0;i<4;i++){
        int r = w*32 + mt*16 + quad*4 + i;
        txtA[(size_t)(b*1024 + k0 + r)*1024 + h*64 + dt*16 + cl] = f2bf(oacc[mt][dt][i]);
      }
}

extern "C" void kernel_launch(void* const* d_in, const int* in_sizes, int n_in,
                              void* d_out, int out_size, void* d_ws, size_t ws_size,
                              hipStream_t stream)
{
  const float* vis = (const float*)d_in[0];
  const float* txt = (const float*)d_in[1];
  const float* Wq  = (const float*)d_in[2];
  const float* Wk  = (const float*)d_in[3];
  const float* Wv  = (const float*)d_in[4];
  const float* Wo  = (const float*)d_in[5];
  float* out = (float*)d_out;

  char* ws = (char*)d_ws;
  const size_t MB = 1u << 20;
  u16* vis16 = (u16*)(ws + 0);          // reused as Vt after projections
  u16* txt16 = (u16*)(ws + 8*MB);       // reused as V2t
  u16* WqT   = (u16*)(ws + 16*MB);
  u16* WkT   = (u16*)(ws + 18*MB);
  u16* WvT   = (u16*)(ws + 20*MB);
  u16* WoT   = (u16*)(ws + 22*MB);
  u16* Qb    = (u16*)(ws + 24*MB);
  u16* Kb    = (u16*)(ws + 32*MB);
  u16* Vb    = (u16*)(ws + 40*MB);      // reused as visA
  u16* V2b   = (u16*)(ws + 48*MB);      // reused as txtA
  float* m_g  = (float*)(ws + 56*MB);
  float* rl_g = (float*)(ws + 56*MB + 262144);
  u16* Vt = vis16; u16* V2t = txt16;
  u16* visA = Vb;  u16* txtA = V2b;

  const int NELT = 4*1024*1024;
  cast_bf16_kernel<<<NELT/1024, 256, 0, stream>>>(vis, vis16, NELT);
  cast_bf16_kernel<<<NELT/1024, 256, 0, stream>>>(txt, txt16, NELT);
  transpose_w_kernel<<<dim3(16,16), 256, 0, stream>>>(Wq, WqT);
  transpose_w_kernel<<<dim3(16,16), 256, 0, stream>>>(Wk, WkT);
  transpose_w_kernel<<<dim3(16,16), 256, 0, stream>>>(Wv, WvT);
  transpose_w_kernel<<<dim3(16,16), 256, 0, stream>>>(Wo, WoT);
  // projections -> head-split bf16 [b][h][s][64]
  gemm_bt_kernel<<<dim3(8,32), 256, 0, stream>>>(vis16, WqT, Qb,  nullptr, 0);
  gemm_bt_kernel<<<dim3(8,32), 256, 0, stream>>>(txt16, WkT, Kb,  nullptr, 0);
  gemm_bt_kernel<<<dim3(8,32), 256, 0, stream>>>(txt16, WvT, Vb,  nullptr, 0);
  gemm_bt_kernel<<<dim3(8,32), 256, 0, stream>>>(vis16, WvT, V2b, nullptr, 0);
  // per-head transposes for PV operands
  transpose_head_kernel<<<dim3(16,64), 256, 0, stream>>>(Vb,  Vt);
  transpose_head_kernel<<<dim3(16,64), 256, 0, stream>>>(V2b, V2t);
  // attention
  attn_vis_kernel<<<dim3(8,64), 256, 0, stream>>>(Qb, Kb, Vt, visA, m_g, rl_g);
  attn_txt_kernel<<<dim3(8,64), 256, 0, stream>>>(Kb, Qb, V2t, m_g, rl_g, txtA);
  // output projections -> f32
  gemm_bt_kernel<<<dim3(8,32), 256, 0, stream>>>(visA, WoT, nullptr, out, 1);
  gemm_bt_kernel<<<dim3(8,32), 256, 0, stream>>>(txtA, WoT, nullptr, out + NELT, 1);
}

// Round 3
// 319.456 us; speedup vs baseline: 1.4020x; 1.3746x over previous
//
#include <hip/hip_runtime.h>

typedef unsigned short u16;
typedef unsigned int u32;
typedef __bf16 bf16x8 __attribute__((ext_vector_type(8)));
typedef float f32x4 __attribute__((ext_vector_type(4)));
typedef u16 u16x4 __attribute__((ext_vector_type(4)));
typedef __attribute__((address_space(1))) void* as1_t;
typedef __attribute__((address_space(3))) void* as3_t;

#define LOG2E 1.4426950408889634f
#define MFMA(a,b,c) __builtin_amdgcn_mfma_f32_16x16x32_bf16(a,b,c,0,0,0)

__device__ __forceinline__ u16 f2bf(float f){
  u32 u = __float_as_uint(f);
  return (u16)((u + 0x7FFFu + ((u >> 16) & 1u)) >> 16);
}
__device__ __forceinline__ float bf2f(u16 x){
  return __uint_as_float(((u32)x) << 16);
}
__device__ __forceinline__ void gld16(const u16* gp, u16* lp){
  __builtin_amdgcn_global_load_lds((as1_t)(u16*)gp, (as3_t)lp, 16, 0, 0);
}

// ---------------- cast f32 -> bf16 ----------------
__global__ void cast_bf16_kernel(const float* __restrict__ in, u16* __restrict__ out, int n){
  int idx = (blockIdx.x*256 + threadIdx.x)*4;
  if(idx < n){
    float4 v = *(const float4*)(in + idx);
    u16x4 o = { f2bf(v.x), f2bf(v.y), f2bf(v.z), f2bf(v.w) };
    *(u16x4*)(out + idx) = o;
  }
}

// ---------------- W [1024x1024] f32 -> WT [n][k] bf16 ----------------
__global__ void transpose_w_kernel(const float* __restrict__ W, u16* __restrict__ WT){
  __shared__ u16 t[64][65];
  int bn = blockIdx.x*64, bk = blockIdx.y*64;
  int c = threadIdx.x & 63, r0 = threadIdx.x >> 6;
  #pragma unroll
  for(int j=0;j<64;j+=4){
    int r = r0 + j;
    t[r][c] = f2bf(W[(bk + r)*1024 + bn + c]);
  }
  __syncthreads();
  #pragma unroll
  for(int j=0;j<64;j+=4){
    int r = r0 + j;
    WT[(bn + r)*1024 + bk + c] = t[c][r];
  }
}

// ---------------- per-head transpose [BH][1024][64] -> [BH][64][1024] ----------------
__global__ void transpose_head_kernel(const u16* __restrict__ in, u16* __restrict__ out){
  __shared__ u16 t[64][65];
  int bh = blockIdx.y; int s0 = blockIdx.x*64;
  int c = threadIdx.x & 63, r0 = threadIdx.x >> 6;
  #pragma unroll
  for(int j=0;j<64;j+=4){
    int r = r0 + j;
    t[r][c] = in[(size_t)bh*65536 + (size_t)(s0 + r)*64 + c];
  }
  __syncthreads();
  #pragma unroll
  for(int j=0;j<64;j+=4){
    int d = r0 + j;
    out[(size_t)bh*65536 + (size_t)d*1024 + s0 + c] = t[c][d];
  }
}

// ---------------- per-head transpose + row-scale: out[d][q] = in[q][d] * rl[q] ----------------
__global__ void transpose_head_scale_kernel(const u16* __restrict__ in, const float* __restrict__ rl,
                                            u16* __restrict__ out){
  __shared__ u16 t[64][65];
  int bh = blockIdx.y; int s0 = blockIdx.x*64;
  int c = threadIdx.x & 63, r0 = threadIdx.x >> 6;
  #pragma unroll
  for(int j=0;j<64;j+=4){
    int r = r0 + j;
    t[r][c] = in[(size_t)bh*65536 + (size_t)(s0 + r)*64 + c];
  }
  __syncthreads();
  float rv = rl[bh*1024 + s0 + c];
  #pragma unroll
  for(int j=0;j<64;j+=4){
    int d = r0 + j;
    out[(size_t)bh*65536 + (size_t)d*1024 + s0 + c] = f2bf(bf2f(t[c][d]) * rv);
  }
}

// ---------------- GEMM: C[M x N] = A[M x 1024] * Bt[n][k], 128x128 tile, N = gridDim.x*128 ----
// mode 0: store bf16 head-split; n<1024 -> C0, n>=1024 -> C1, layout [b][h][s][64]
// mode 1: store f32 row-major  Cf[m][n]
__global__ __launch_bounds__(256, 2)
void gemm_bt_kernel(const u16* __restrict__ A, const u16* __restrict__ Bt,
                    u16* __restrict__ C0, u16* __restrict__ C1, float* __restrict__ Cf, int mode)
{
  __shared__ u16 lds[8192];
  u16* Al = lds; u16* Bl = lds + 4096;
  const int tid = threadIdx.x, w = tid >> 6, lane = tid & 63;
  const int quad = lane >> 4, cl = lane & 15;
  const int bm = blockIdx.y*128, bn = blockIdx.x*128;
  const int wm = (w >> 1)*64, wn = (w & 1)*64;
  const int K = 1024;
  f32x4 acc[4][4];
  #pragma unroll
  for(int a=0;a<4;a++)
    #pragma unroll
    for(int b=0;b<4;b++){ f32x4 z = {0.f,0.f,0.f,0.f}; acc[a][b] = z; }

  for(int k0=0;k0<K;k0+=32){
    __syncthreads();
    #pragma unroll
    for(int i=0;i<2;i++){
      int slot = (w*2+i)*64 + lane;
      int c = slot >> 7, r = slot & 127;
      gld16(A  + (size_t)(bm + r)*K + k0 + c*8, Al + (w*2+i)*512);
      gld16(Bt + (size_t)(bn + r)*K + k0 + c*8, Bl + (w*2+i)*512);
    }
    __syncthreads();
    bf16x8 af[4], bfv[4];
    #pragma unroll
    for(int mt=0;mt<4;mt++) af[mt]  = *(const bf16x8*)(Al + (quad*128 + wm + mt*16 + cl)*8);
    #pragma unroll
    for(int nt=0;nt<4;nt++) bfv[nt] = *(const bf16x8*)(Bl + (quad*128 + wn + nt*16 + cl)*8);
    #pragma unroll
    for(int mt=0;mt<4;mt++)
      #pragma unroll
      for(int nt=0;nt<4;nt++)
        acc[mt][nt] = MFMA(af[mt], bfv[nt], acc[mt][nt]);
  }
  #pragma unroll
  for(int mt=0;mt<4;mt++)
    #pragma unroll
    for(int nt=0;nt<4;nt++)
      #pragma unroll
      for(int i=0;i<4;i++){
        int m = bm + wm + mt*16 + quad*4 + i;
        int n = bn + wn + nt*16 + cl;
        float v = acc[mt][nt][i];
        if(mode == 0){
          int nn = n & 1023;
          u16* dst = (n >> 10) ? C1 : C0;
          int b = m >> 10, s = m & 1023, h = nn >> 6, d = nn & 63;
          dst[(((size_t)(b*16 + h)*1024 + s) << 6) + d] = f2bf(v);
        } else {
          Cf[(size_t)m*1024 + n] = v;
        }
      }
}

// ---------------- attention (vis): no-max softmax, S^T tiles, packed P, swizzled V ----------------
// block: 128 q-rows (wave w owns q = w*32..w*32+31); streams 16 k-tiles of 64.
__global__ __launch_bounds__(256, 4)
void attn_vis_kernel(const u16* __restrict__ Q, const u16* __restrict__ Kc,
                     const u16* __restrict__ Vt, u16* __restrict__ visA,
                     float* __restrict__ rl_g)
{
  __shared__ u16 lds[17408];   // 34816 B
  u16* Pl  = lds;              // P[q=128][72] (9216 u16); Q staged here first ([c8][128][8]=8192)
  u16* Kst = lds + 9216;       // [c8][64][8] = 4096 u16
  u16* Vst = lds + 13312;      // [d=64][ch^=8][8] swizzled = 4096 u16
  const int tid = threadIdx.x, w = tid>>6, lane = tid&63;
  const int quad = lane>>4, cl = lane&15;
  const int bh = blockIdx.y, q0 = blockIdx.x*128;
  const u16* Qh  = Q  + (size_t)bh*65536;
  const u16* Kh  = Kc + (size_t)bh*65536;
  const u16* Vth = Vt + (size_t)bh*65536;

  // stage Q tile (128x64) -> Pl, read persistent B-fragments (Q[q][d])
  #pragma unroll
  for(int i=0;i<4;i++){
    int slot = (w*4+i)*64 + lane;
    int c = slot >> 7, r = slot & 127;
    gld16(Qh + (size_t)(q0 + r)*64 + c*8, Pl + slot*8);
  }
  __syncthreads();
  bf16x8 qf[2][2];
  #pragma unroll
  for(int ntq=0;ntq<2;ntq++)
    #pragma unroll
    for(int kk=0;kk<2;kk++)
      qf[ntq][kk] = *(const bf16x8*)(Pl + ((kk*4+quad)*128 + w*32 + ntq*16 + cl)*8);
  __syncthreads();   // Pl now becomes the P buffer

  float lrun[2] = {0.f, 0.f};
  f32x4 oacc[2][4];
  #pragma unroll
  for(int mt=0;mt<2;mt++)
    #pragma unroll
    for(int dt=0;dt<4;dt++){ f32x4 z = {0.f,0.f,0.f,0.f}; oacc[mt][dt] = z; }

  for(int kt=0;kt<16;kt++){
    __syncthreads();
    #pragma unroll
    for(int i=0;i<2;i++){
      int slot = (w*2+i)*64 + lane;
      { int c = slot >> 6, r = slot & 63;
        gld16(Kh + (size_t)(kt*64 + r)*64 + c*8, Kst + slot*8); }
      { int d = slot >> 3, ch = slot & 7;
        gld16(Vth + (size_t)d*1024 + kt*64 + (ch^(d&7))*8, Vst + slot*8); }
    }
    __syncthreads();
    // S^T tiles: D[m = k-rows][n = q-cols]; A = K-frag (streamed), B = Q-frag (persistent)
    #pragma unroll
    for(int mtk=0;mtk<4;mtk++){
      f32x4 s[2];
      { f32x4 z = {0.f,0.f,0.f,0.f}; s[0] = z; s[1] = z; }
      #pragma unroll
      for(int kk=0;kk<2;kk++){
        bf16x8 ka = *(const bf16x8*)(Kst + ((kk*4+quad)*64 + mtk*16 + cl)*8);
        s[0] = MFMA(ka, qf[0][kk], s[0]);
        s[1] = MFMA(ka, qf[1][kk], s[1]);
      }
      #pragma unroll
      for(int ntq=0;ntq<2;ntq++){
        u16x4 pk;
        float ps = 0.f;
        #pragma unroll
        for(int i=0;i<4;i++){
          float p = exp2f(s[ntq][i]*LOG2E);
          ps += p;
          pk[i] = f2bf(p);
        }
        lrun[ntq] += ps;
        // P[q][k]-major: q = w*32+ntq*16+cl (wave-private rows), k = mtk*16+quad*4..+3
        *(u16x4*)(Pl + (w*32 + ntq*16 + cl)*72 + mtk*16 + quad*4) = pk;
      }
    }
    // O[q][d] += P @ V^T  (A = P rows, B = V^T swizzled; same-wave DS write->read)
    bf16x8 pa[2][2];
    #pragma unroll
    for(int mt=0;mt<2;mt++)
      #pragma unroll
      for(int kk=0;kk<2;kk++)
        pa[mt][kk] = *(const bf16x8*)(Pl + (w*32 + mt*16 + cl)*72 + kk*32 + quad*8);
    #pragma unroll
    for(int dt=0;dt<4;dt++){
      int d = dt*16 + cl;
      #pragma unroll
      for(int kk=0;kk<2;kk++){
        bf16x8 vb = *(const bf16x8*)(Vst + d*64 + (((kk*4+quad)^(d&7))*8));
        oacc[0][dt] = MFMA(pa[0][kk], vb, oacc[0][dt]);
        oacc[1][dt] = MFMA(pa[1][kk], vb, oacc[1][dt]);
      }
    }
  }
  // finalize l across quads (per q = w*32 + ntq*16 + cl)
  #pragma unroll
  for(int ntq=0;ntq<2;ntq++){
    lrun[ntq] += __shfl_xor(lrun[ntq], 16, 64);
    lrun[ntq] += __shfl_xor(lrun[ntq], 32, 64);
  }
  float rl[2] = {1.f/lrun[0], 1.f/lrun[1]};
  if(quad == 0){
    rl_g[bh*1024 + q0 + w*32 + cl]      = rl[0];
    rl_g[bh*1024 + q0 + w*32 + 16 + cl] = rl[1];
  }
  const int b = bh >> 4, h = bh & 15;
  #pragma unroll
  for(int mt=0;mt<2;mt++)
    #pragma unroll
    for(int i=0;i<4;i++){
      float rr = __shfl(rl[mt], quad*4 + i, 16);
      int q = q0 + w*32 + mt*16 + quad*4 + i;
      #pragma unroll
      for(int dt=0;dt<4;dt++)
        visA[(size_t)(b*1024 + q)*1024 + h*64 + dt*16 + cl] = f2bf(oacc[mt][dt][i]*rr);
    }
}

// ---------------- attention (txt): mirror — S tiles, P^T packed, V2' pre-scaled by rl ----------------
// block: 128 k-cols (wave w owns k = w*32..+31); streams 16 q-tiles of 64.
__global__ __launch_bounds__(256, 4)
void attn_txt_kernel(const u16* __restrict__ Kc, const u16* __restrict__ Q,
                     const u16* __restrict__ V2t, u16* __restrict__ txtA)
{
  __shared__ u16 lds[17408];
  u16* Pl  = lds;              // P^T[k=128][72]; K-block staged here first
  u16* Qst = lds + 9216;       // [c8][64][8]
  u16* Vst = lds + 13312;      // [d][ch^][8] swizzled (contraction = q)
  const int tid = threadIdx.x, w = tid>>6, lane = tid&63;
  const int quad = lane>>4, cl = lane&15;
  const int bh = blockIdx.y, k0 = blockIdx.x*128;
  const u16* Kh  = Kc  + (size_t)bh*65536;
  const u16* Qh  = Q   + (size_t)bh*65536;
  const u16* Vth = V2t + (size_t)bh*65536;

  #pragma unroll
  for(int i=0;i<4;i++){
    int slot = (w*4+i)*64 + lane;
    int c = slot >> 7, r = slot & 127;
    gld16(Kh + (size_t)(k0 + r)*64 + c*8, Pl + slot*8);
  }
  __syncthreads();
  bf16x8 kb[2][2];
  #pragma unroll
  for(int ntk=0;ntk<2;ntk++)
    #pragma unroll
    for(int kk=0;kk<2;kk++)
      kb[ntk][kk] = *(const bf16x8*)(Pl + ((kk*4+quad)*128 + w*32 + ntk*16 + cl)*8);
  __syncthreads();

  f32x4 oacc[2][4];
  #pragma unroll
  for(int mt=0;mt<2;mt++)
    #pragma unroll
    for(int dt=0;dt<4;dt++){ f32x4 z = {0.f,0.f,0.f,0.f}; oacc[mt][dt] = z; }

  for(int qt=0;qt<16;qt++){
    __syncthreads();
    #pragma unroll
    for(int i=0;i<2;i++){
      int slot = (w*2+i)*64 + lane;
      { int c = slot >> 6, r = slot & 63;
        gld16(Qh + (size_t)(qt*64 + r)*64 + c*8, Qst + slot*8); }
      { int d = slot >> 3, ch = slot & 7;
        gld16(Vth + (size_t)d*1024 + qt*64 + (ch^(d&7))*8, Vst + slot*8); }
    }
    __syncthreads();
    // S tiles: D[m = q-rows][n = k-cols]; A = Q-frag (streamed), B = K-frag (persistent)
    #pragma unroll
    for(int mtq=0;mtq<4;mtq++){
      f32x4 s[2];
      { f32x4 z = {0.f,0.f,0.f,0.f}; s[0] = z; s[1] = z; }
      #pragma unroll
      for(int kk=0;kk<2;kk++){
        bf16x8 qa = *(const bf16x8*)(Qst + ((kk*4+quad)*64 + mtq*16 + cl)*8);
        s[0] = MFMA(qa, kb[0][kk], s[0]);
        s[1] = MFMA(qa, kb[1][kk], s[1]);
      }
      #pragma unroll
      for(int ntk=0;ntk<2;ntk++){
        u16x4 pk;
        #pragma unroll
        for(int i=0;i<4;i++)
          pk[i] = f2bf(exp2f(s[ntk][i]*LOG2E));
        // P^T[k][q]-major: k = w*32+ntk*16+cl (wave-private rows), q = mtq*16+quad*4..+3
        *(u16x4*)(Pl + (w*32 + ntk*16 + cl)*72 + mtq*16 + quad*4) = pk;
      }
    }
    // O[k][d] += P^T @ V2'  (contraction over q)
    bf16x8 pa[2][2];
    #pragma unroll
    for(int mt=0;mt<2;mt++)
      #pragma unroll
      for(int kk=0;kk<2;kk++)
        pa[mt][kk] = *(const bf16x8*)(Pl + (w*32 + mt*16 + cl)*72 + kk*32 + quad*8);
    #pragma unroll
    for(int dt=0;dt<4;dt++){
      int d = dt*16 + cl;
      #pragma unroll
      for(int kk=0;kk<2;kk++){
        bf16x8 vb = *(const bf16x8*)(Vst + d*64 + (((kk*4+quad)^(d&7))*8));
        oacc[0][dt] = MFMA(pa[0][kk], vb, oacc[0][dt]);
        oacc[1][dt] = MFMA(pa[1][kk], vb, oacc[1][dt]);
      }
    }
  }
  const int b = bh >> 4, h = bh & 15;
  #pragma unroll
  for(int mt=0;mt<2;mt++)
    #pragma unroll
    for(int i=0;i<4;i++){
      int k = k0 + w*32 + mt*16 + quad*4 + i;
      #pragma unroll
      for(int dt=0;dt<4;dt++)
        txtA[(size_t)(b*1024 + k)*1024 + h*64 + dt*16 + cl] = f2bf(oacc[mt][dt][i]);
    }
}

extern "C" void kernel_launch(void* const* d_in, const int* in_sizes, int n_in,
                              void* d_out, int out_size, void* d_ws, size_t ws_size,
                              hipStream_t stream)
{
  const float* vis = (const float*)d_in[0];
  const float* txt = (const float*)d_in[1];
  const float* Wq  = (const float*)d_in[2];
  const float* Wk  = (const float*)d_in[3];
  const float* Wv  = (const float*)d_in[4];
  const float* Wo  = (const float*)d_in[5];
  float* out = (float*)d_out;

  char* ws = (char*)d_ws;
  const size_t MB = 1u << 20;
  u16* vis16 = (u16*)(ws + 0);           // later: Vt
  u16* txt16 = (u16*)(ws + 8*MB);        // later: V2t'
  u16* Wvis  = (u16*)(ws + 16*MB);       // [WqT | WvT]; later: WoT
  u16* Wtxt  = (u16*)(ws + 20*MB);       // [WkT | WvT]
  u16* Qb    = (u16*)(ws + 24*MB);
  u16* Kb    = (u16*)(ws + 32*MB);
  u16* Vb    = (u16*)(ws + 40*MB);       // later: visA
  u16* V2b   = (u16*)(ws + 48*MB);       // later: txtA
  float* rl_g = (float*)(ws + 56*MB);
  u16* Vt = vis16; u16* V2t = txt16;
  u16* visA = Vb;  u16* txtA = V2b;

  const int NELT = 4*1024*1024;
  cast_bf16_kernel<<<NELT/1024, 256, 0, stream>>>(vis, vis16, NELT);
  cast_bf16_kernel<<<NELT/1024, 256, 0, stream>>>(txt, txt16, NELT);
  transpose_w_kernel<<<dim3(16,16), 256, 0, stream>>>(Wq, Wvis);
  transpose_w_kernel<<<dim3(16,16), 256, 0, stream>>>(Wv, Wvis + 1048576);
  transpose_w_kernel<<<dim3(16,16), 256, 0, stream>>>(Wk, Wtxt);
  transpose_w_kernel<<<dim3(16,16), 256, 0, stream>>>(Wv, Wtxt + 1048576);
  // merged projections (N=2048): vis -> [Q | V2], txt -> [K | V]
  gemm_bt_kernel<<<dim3(16,32), 256, 0, stream>>>(vis16, Wvis, Qb, V2b, nullptr, 0);
  gemm_bt_kernel<<<dim3(16,32), 256, 0, stream>>>(txt16, Wtxt, Kb, Vb,  nullptr, 0);
  // WoT into the now-dead Wvis slot
  transpose_w_kernel<<<dim3(16,16), 256, 0, stream>>>(Wo, Wvis);
  // V^T for attn_vis (vis16 dead)
  transpose_head_kernel<<<dim3(16,64), 256, 0, stream>>>(Vb, Vt);
  // attention vis (produces rl)
  attn_vis_kernel<<<dim3(8,64), 256, 0, stream>>>(Qb, Kb, Vt, visA, rl_g);
  // V2'^T = (rl * V2)^T  (txt16 dead)
  transpose_head_scale_kernel<<<dim3(16,64), 256, 0, stream>>>(V2b, rl_g, V2t);
  // attention txt
  attn_txt_kernel<<<dim3(8,64), 256, 0, stream>>>(Kb, Qb, V2t, txtA);
  // merged output projection: M=8192 over visA||txtA (contiguous), f32 out
  gemm_bt_kernel<<<dim3(8,64), 256, 0, stream>>>(visA, Wvis, nullptr, nullptr, out, 1);
}

// Round 4
// 286.412 us; speedup vs baseline: 1.5637x; 1.1154x over previous
//
#include <hip/hip_runtime.h>

typedef unsigned short u16;
typedef unsigned int u32;
typedef __bf16 bf16x8 __attribute__((ext_vector_type(8)));
typedef float f32x4 __attribute__((ext_vector_type(4)));
typedef u16 u16x4 __attribute__((ext_vector_type(4)));
typedef __attribute__((address_space(1))) void* as1_t;
typedef __attribute__((address_space(3))) void* as3_t;

#define LOG2E 1.4426950408889634f
#define MFMA(a,b,c) __builtin_amdgcn_mfma_f32_16x16x32_bf16(a,b,c,0,0,0)

__device__ __forceinline__ u16 f2bf(float f){
  u32 u = __float_as_uint(f);
  return (u16)((u + 0x7FFFu + ((u >> 16) & 1u)) >> 16);
}
__device__ __forceinline__ float bf2f(u16 x){
  return __uint_as_float(((u32)x) << 16);
}
#if __has_builtin(__builtin_amdgcn_cvt_pk_bf16_f32)
__device__ __forceinline__ u16x4 pk4(float a, float b, float c, float d){
  auto lo = __builtin_amdgcn_cvt_pk_bf16_f32(a,b);
  auto hi = __builtin_amdgcn_cvt_pk_bf16_f32(c,d);
  union { u16x4 v; u32 w[2]; } u;
  u.w[0] = __builtin_bit_cast(u32, lo);
  u.w[1] = __builtin_bit_cast(u32, hi);
  return u.v;
}
#else
__device__ __forceinline__ u16x4 pk4(float a, float b, float c, float d){
  u16x4 r = { f2bf(a), f2bf(b), f2bf(c), f2bf(d) };
  return r;
}
#endif
__device__ __forceinline__ void gld16(const u16* gp, u16* lp){
  __builtin_amdgcn_global_load_lds((as1_t)(u16*)gp, (as3_t)lp, 16, 0, 0);
}

// ---------------- cast f32 -> bf16 (both inputs, one launch) ----------------
__global__ void cast2_bf16_kernel(const float* __restrict__ a, u16* __restrict__ oa,
                                  const float* __restrict__ b, u16* __restrict__ ob){
  int half = gridDim.x >> 1;
  int bid = blockIdx.x;
  const float* src; u16* dst;
  if(bid >= half){ src = b; dst = ob; bid -= half; }
  else           { src = a; dst = oa; }
  int idx = (bid*256 + threadIdx.x)*4;
  float4 v = *(const float4*)(src + idx);
  *(u16x4*)(dst + idx) = pk4(v.x, v.y, v.z, v.w);
}

// ---------------- 5 weight transposes, one launch (z-indexed) ----------------
__global__ void transpose_w5_kernel(const float* __restrict__ W0, const float* __restrict__ W1,
                                    const float* __restrict__ W2, const float* __restrict__ W3,
                                    const float* __restrict__ W4,
                                    u16* __restrict__ T0, u16* __restrict__ T1,
                                    u16* __restrict__ T2, u16* __restrict__ T3,
                                    u16* __restrict__ T4){
  const float* W; u16* WT;
  switch(blockIdx.z){
    case 0: W = W0; WT = T0; break;
    case 1: W = W1; WT = T1; break;
    case 2: W = W2; WT = T2; break;
    case 3: W = W3; WT = T3; break;
    default: W = W4; WT = T4; break;
  }
  __shared__ u16 t[64][65];
  int bn = blockIdx.x*64, bk = blockIdx.y*64;
  int c = threadIdx.x & 63, r0 = threadIdx.x >> 6;
  #pragma unroll
  for(int j=0;j<64;j+=4){
    int r = r0 + j;
    t[r][c] = f2bf(W[(bk + r)*1024 + bn + c]);
  }
  __syncthreads();
  #pragma unroll
  for(int j=0;j<64;j+=4){
    int r = r0 + j;
    WT[(bn + r)*1024 + bk + c] = t[c][r];
  }
}

// ---------------- per-head transpose [BH][1024][64] -> [BH][64][1024] ----------------
__global__ void transpose_head_kernel(const u16* __restrict__ in, u16* __restrict__ out){
  __shared__ u16 t[64][65];
  int bh = blockIdx.y; int s0 = blockIdx.x*64;
  int c = threadIdx.x & 63, r0 = threadIdx.x >> 6;
  #pragma unroll
  for(int j=0;j<64;j+=4){
    int r = r0 + j;
    t[r][c] = in[(size_t)bh*65536 + (size_t)(s0 + r)*64 + c];
  }
  __syncthreads();
  #pragma unroll
  for(int j=0;j<64;j+=4){
    int d = r0 + j;
    out[(size_t)bh*65536 + (size_t)d*1024 + s0 + c] = t[c][d];
  }
}

// ---------------- per-head transpose + row-scale: out[d][q] = in[q][d] * rl[q] ----------------
__global__ void transpose_head_scale_kernel(const u16* __restrict__ in, const float* __restrict__ rl,
                                            u16* __restrict__ out){
  __shared__ u16 t[64][65];
  int bh = blockIdx.y; int s0 = blockIdx.x*64;
  int c = threadIdx.x & 63, r0 = threadIdx.x >> 6;
  #pragma unroll
  for(int j=0;j<64;j+=4){
    int r = r0 + j;
    t[r][c] = in[(size_t)bh*65536 + (size_t)(s0 + r)*64 + c];
  }
  __syncthreads();
  float rv = rl[bh*1024 + s0 + c];
  #pragma unroll
  for(int j=0;j<64;j+=4){
    int d = r0 + j;
    out[(size_t)bh*65536 + (size_t)d*1024 + s0 + c] = f2bf(bf2f(t[c][d]) * rv);
  }
}

// ---------------- GEMM: C[M x N] = A[M x 1024] * Bt[n][k], 128x128 tile ----
// mode 0: store bf16 head-split; n<1024 -> C0, n>=1024 -> C1, layout [b][h][s][64]
// mode 1: store f32 row-major  Cf[m][n]
__global__ __launch_bounds__(256, 2)
void gemm_bt_kernel(const u16* __restrict__ A, const u16* __restrict__ Bt,
                    u16* __restrict__ C0, u16* __restrict__ C1, float* __restrict__ Cf, int mode)
{
  __shared__ u16 lds[8192];
  u16* Al = lds; u16* Bl = lds + 4096;
  const int tid = threadIdx.x, w = tid >> 6, lane = tid & 63;
  const int quad = lane >> 4, cl = lane & 15;
  const int bm = blockIdx.y*128, bn = blockIdx.x*128;
  const int wm = (w >> 1)*64, wn = (w & 1)*64;
  const int K = 1024;
  f32x4 acc[4][4];
  #pragma unroll
  for(int a=0;a<4;a++)
    #pragma unroll
    for(int b=0;b<4;b++){ f32x4 z = {0.f,0.f,0.f,0.f}; acc[a][b] = z; }

  for(int k0=0;k0<K;k0+=32){
    __syncthreads();
    #pragma unroll
    for(int i=0;i<2;i++){
      int slot = (w*2+i)*64 + lane;
      int c = slot >> 7, r = slot & 127;
      gld16(A  + (size_t)(bm + r)*K + k0 + c*8, Al + (w*2+i)*512);
      gld16(Bt + (size_t)(bn + r)*K + k0 + c*8, Bl + (w*2+i)*512);
    }
    __syncthreads();
    bf16x8 af[4], bfv[4];
    #pragma unroll
    for(int mt=0;mt<4;mt++) af[mt]  = *(const bf16x8*)(Al + (quad*128 + wm + mt*16 + cl)*8);
    #pragma unroll
    for(int nt=0;nt<4;nt++) bfv[nt] = *(const bf16x8*)(Bl + (quad*128 + wn + nt*16 + cl)*8);
    #pragma unroll
    for(int mt=0;mt<4;mt++)
      #pragma unroll
      for(int nt=0;nt<4;nt++)
        acc[mt][nt] = MFMA(af[mt], bfv[nt], acc[mt][nt]);
  }
  #pragma unroll
  for(int mt=0;mt<4;mt++)
    #pragma unroll
    for(int nt=0;nt<4;nt++)
      #pragma unroll
      for(int i=0;i<4;i++){
        int m = bm + wm + mt*16 + quad*4 + i;
        int n = bn + wn + nt*16 + cl;
        float v = acc[mt][nt][i];
        if(mode == 0){
          int nn = n & 1023;
          u16* dst = (n >> 10) ? C1 : C0;
          int b = m >> 10, s = m & 1023, h = nn >> 6, d = nn & 63;
          dst[(((size_t)(b*16 + h)*1024 + s) << 6) + d] = f2bf(v);
        } else {
          Cf[(size_t)m*1024 + n] = v;
        }
      }
}

// ---------------- attention (vis): 8 waves x 16 q-rows, no-max softmax, S^T tiles ----------------
__global__ __launch_bounds__(512, 4)
void attn_vis_kernel(const u16* __restrict__ Q, const u16* __restrict__ Kc,
                     const u16* __restrict__ Vt, u16* __restrict__ visA,
                     float* __restrict__ rl_g)
{
  __shared__ u16 lds[17408];   // 34816 B
  u16* Pl  = lds;              // P[q=128][72]; Q staged here first ([c8][128][8]=8192)
  u16* Kst = lds + 9216;       // [c8][64][8] = 4096 u16
  u16* Vst = lds + 13312;      // [d=64][ch^][8] swizzled = 4096 u16
  const int tid = threadIdx.x, w = tid>>6, lane = tid&63;
  const int quad = lane>>4, cl = lane&15;
  const int bh = blockIdx.y, q0 = blockIdx.x*128;
  const u16* Qh  = Q  + (size_t)bh*65536;
  const u16* Kh  = Kc + (size_t)bh*65536;
  const u16* Vth = Vt + (size_t)bh*65536;

  // stage Q tile (128x64) -> Pl; wave w reads its persistent B-fragment (16 q-cols)
  #pragma unroll
  for(int i=0;i<2;i++){
    int slot = i*512 + tid;
    int c = slot >> 7, r = slot & 127;
    gld16(Qh + (size_t)(q0 + r)*64 + c*8, Pl + slot*8);
  }
  __syncthreads();
  bf16x8 qf[2];
  #pragma unroll
  for(int kk=0;kk<2;kk++)
    qf[kk] = *(const bf16x8*)(Pl + ((kk*4+quad)*128 + w*16 + cl)*8);
  __syncthreads();   // Pl now becomes the P buffer

  float lrun = 0.f;
  f32x4 oacc[4];
  #pragma unroll
  for(int dt=0;dt<4;dt++){ f32x4 z = {0.f,0.f,0.f,0.f}; oacc[dt] = z; }

  for(int kt=0;kt<16;kt++){
    __syncthreads();
    {
      int slot = tid;
      { int c = slot >> 6, r = slot & 63;
        gld16(Kh + (size_t)(kt*64 + r)*64 + c*8, Kst + slot*8); }
      { int d = slot >> 3, ch = slot & 7;
        gld16(Vth + (size_t)d*1024 + kt*64 + (ch^(d&7))*8, Vst + slot*8); }
    }
    __syncthreads();
    // S^T tiles: D[m = k][n = q(wave's 16)]; A = K-frag (streamed), B = qf (persistent)
    #pragma unroll
    for(int mtk=0;mtk<4;mtk++){
      f32x4 s = {0.f,0.f,0.f,0.f};
      #pragma unroll
      for(int kk=0;kk<2;kk++){
        bf16x8 ka = *(const bf16x8*)(Kst + ((kk*4+quad)*64 + mtk*16 + cl)*8);
        s = MFMA(ka, qf[kk], s);
      }
      float p0 = __builtin_amdgcn_exp2f(s[0]*LOG2E);
      float p1 = __builtin_amdgcn_exp2f(s[1]*LOG2E);
      float p2 = __builtin_amdgcn_exp2f(s[2]*LOG2E);
      float p3 = __builtin_amdgcn_exp2f(s[3]*LOG2E);
      lrun += (p0+p1)+(p2+p3);
      // P[q][k]: q = w*16+cl (wave-private rows), k = mtk*16 + quad*4..+3
      *(u16x4*)(Pl + (w*16 + cl)*72 + mtk*16 + quad*4) = pk4(p0,p1,p2,p3);
    }
    // O[q][d] += P @ V^T  (same-wave DS write->read on private rows)
    bf16x8 pa[2];
    #pragma unroll
    for(int kk=0;kk<2;kk++)
      pa[kk] = *(const bf16x8*)(Pl + (w*16 + cl)*72 + kk*32 + quad*8);
    #pragma unroll
    for(int dt=0;dt<4;dt++){
      int d = dt*16 + cl;
      #pragma unroll
      for(int kk=0;kk<2;kk++){
        bf16x8 vb = *(const bf16x8*)(Vst + d*64 + (((kk*4+quad)^(d&7))*8));
        oacc[dt] = MFMA(pa[kk], vb, oacc[dt]);
      }
    }
  }
  // finalize l across quads (per q = w*16 + cl)
  lrun += __shfl_xor(lrun, 16, 64);
  lrun += __shfl_xor(lrun, 32, 64);
  float rl = 1.f/lrun;
  if(quad == 0) rl_g[bh*1024 + q0 + w*16 + cl] = rl;
  const int b = bh >> 4, h = bh & 15;
  #pragma unroll
  for(int i=0;i<4;i++){
    float rr = __shfl(rl, quad*4 + i, 16);
    int q = q0 + w*16 + quad*4 + i;
    #pragma unroll
    for(int dt=0;dt<4;dt++)
      visA[(size_t)(b*1024 + q)*1024 + h*64 + dt*16 + cl] = f2bf(oacc[dt][i]*rr);
  }
}

// ---------------- attention (txt): 8 waves x 16 k-rows, V2' pre-scaled by rl ----------------
__global__ __launch_bounds__(512, 4)
void attn_txt_kernel(const u16* __restrict__ Kc, const u16* __restrict__ Q,
                     const u16* __restrict__ V2t, u16* __restrict__ txtA)
{
  __shared__ u16 lds[17408];
  u16* Pl  = lds;              // P^T[k=128][72]; K-block staged here first
  u16* Qst = lds + 9216;       // [c8][64][8]
  u16* Vst = lds + 13312;      // [d][ch^][8] swizzled (contraction = q)
  const int tid = threadIdx.x, w = tid>>6, lane = tid&63;
  const int quad = lane>>4, cl = lane&15;
  const int bh = blockIdx.y, k0 = blockIdx.x*128;
  const u16* Kh  = Kc  + (size_t)bh*65536;
  const u16* Qh  = Q   + (size_t)bh*65536;
  const u16* Vth = V2t + (size_t)bh*65536;

  #pragma unroll
  for(int i=0;i<2;i++){
    int slot = i*512 + tid;
    int c = slot >> 7, r = slot & 127;
    gld16(Kh + (size_t)(k0 + r)*64 + c*8, Pl + slot*8);
  }
  __syncthreads();
  bf16x8 kb[2];
  #pragma unroll
  for(int kk=0;kk<2;kk++)
    kb[kk] = *(const bf16x8*)(Pl + ((kk*4+quad)*128 + w*16 + cl)*8);
  __syncthreads();

  f32x4 oacc[4];
  #pragma unroll
  for(int dt=0;dt<4;dt++){ f32x4 z = {0.f,0.f,0.f,0.f}; oacc[dt] = z; }

  for(int qt=0;qt<16;qt++){
    __syncthreads();
    {
      int slot = tid;
      { int c = slot >> 6, r = slot & 63;
        gld16(Qh + (size_t)(qt*64 + r)*64 + c*8, Qst + slot*8); }
      { int d = slot >> 3, ch = slot & 7;
        gld16(Vth + (size_t)d*1024 + qt*64 + (ch^(d&7))*8, Vst + slot*8); }
    }
    __syncthreads();
    // S tiles: D[m = q][n = k(wave's 16)]; A = Q-frag (streamed), B = kb (persistent)
    #pragma unroll
    for(int mtq=0;mtq<4;mtq++){
      f32x4 s = {0.f,0.f,0.f,0.f};
      #pragma unroll
      for(int kk=0;kk<2;kk++){
        bf16x8 qa = *(const bf16x8*)(Qst + ((kk*4+quad)*64 + mtq*16 + cl)*8);
        s = MFMA(qa, kb[kk], s);
      }
      float p0 = __builtin_amdgcn_exp2f(s[0]*LOG2E);
      float p1 = __builtin_amdgcn_exp2f(s[1]*LOG2E);
      float p2 = __builtin_amdgcn_exp2f(s[2]*LOG2E);
      float p3 = __builtin_amdgcn_exp2f(s[3]*LOG2E);
      // P^T[k][q]: k = w*16+cl (wave-private rows), q = mtq*16 + quad*4..+3
      *(u16x4*)(Pl + (w*16 + cl)*72 + mtq*16 + quad*4) = pk4(p0,p1,p2,p3);
    }
    // O[k][d] += P^T @ V2'  (contraction over q)
    bf16x8 pa[2];
    #pragma unroll
    for(int kk=0;kk<2;kk++)
      pa[kk] = *(const bf16x8*)(Pl + (w*16 + cl)*72 + kk*32 + quad*8);
    #pragma unroll
    for(int dt=0;dt<4;dt++){
      int d = dt*16 + cl;
      #pragma unroll
      for(int kk=0;kk<2;kk++){
        bf16x8 vb = *(const bf16x8*)(Vst + d*64 + (((kk*4+quad)^(d&7))*8));
        oacc[dt] = MFMA(pa[kk], vb, oacc[dt]);
      }
    }
  }
  const int b = bh >> 4, h = bh & 15;
  #pragma unroll
  for(int i=0;i<4;i++){
    int k = k0 + w*16 + quad*4 + i;
    #pragma unroll
    for(int dt=0;dt<4;dt++)
      txtA[(size_t)(b*1024 + k)*1024 + h*64 + dt*16 + cl] = f2bf(oacc[dt][i]);
  }
}

extern "C" void kernel_launch(void* const* d_in, const int* in_sizes, int n_in,
                              void* d_out, int out_size, void* d_ws, size_t ws_size,
                              hipStream_t stream)
{
  const float* vis = (const float*)d_in[0];
  const float* txt = (const float*)d_in[1];
  const float* Wq  = (const float*)d_in[2];
  const float* Wk  = (const float*)d_in[3];
  const float* Wv  = (const float*)d_in[4];
  const float* Wo  = (const float*)d_in[5];
  float* out = (float*)d_out;

  char* ws = (char*)d_ws;
  const size_t MB = 1u << 20;
  u16* vis16 = (u16*)(ws + 0);           // later: Vt
  u16* txt16 = (u16*)(ws + 8*MB);        // later: V2t'
  u16* Wvis  = (u16*)(ws + 16*MB);       // [WqT | WvT]
  u16* Wtxt  = (u16*)(ws + 20*MB);       // [WkT | WvT]
  u16* Qb    = (u16*)(ws + 24*MB);
  u16* Kb    = (u16*)(ws + 32*MB);
  u16* Vb    = (u16*)(ws + 40*MB);       // later: visA
  u16* V2b   = (u16*)(ws + 48*MB);       // later: txtA
  float* rl_g = (float*)(ws + 56*MB);
  u16* WoT   = (u16*)(ws + 57*MB);
  u16* Vt = vis16; u16* V2t = txt16;
  u16* visA = Vb;  u16* txtA = V2b;

  // 1: cast both inputs
  cast2_bf16_kernel<<<8192, 256, 0, stream>>>(vis, vis16, txt, txt16);
  // 2: all 5 weight transposes
  transpose_w5_kernel<<<dim3(16,16,5), 256, 0, stream>>>(
      Wq, Wv, Wk, Wv, Wo,
      Wvis, Wvis + 1048576, Wtxt, Wtxt + 1048576, WoT);
  // 3-4: merged projections (N=2048): vis -> [Q | V2], txt -> [K | V]
  gemm_bt_kernel<<<dim3(16,32), 256, 0, stream>>>(vis16, Wvis, Qb, V2b, nullptr, 0);
  gemm_bt_kernel<<<dim3(16,32), 256, 0, stream>>>(txt16, Wtxt, Kb, Vb,  nullptr, 0);
  // 5: V^T for attn_vis (vis16 dead)
  transpose_head_kernel<<<dim3(16,64), 256, 0, stream>>>(Vb, Vt);
  // 6: attention vis (produces rl)
  attn_vis_kernel<<<dim3(8,64), 512, 0, stream>>>(Qb, Kb, Vt, visA, rl_g);
  // 7: V2'^T = (rl * V2)^T  (txt16 dead)
  transpose_head_scale_kernel<<<dim3(16,64), 256, 0, stream>>>(V2b, rl_g, V2t);
  // 8: attention txt
  attn_txt_kernel<<<dim3(8,64), 512, 0, stream>>>(Kb, Qb, V2t, txtA);
  // 9: merged output projection: M=8192 over visA||txtA (contiguous), f32 out
  gemm_bt_kernel<<<dim3(8,64), 256, 0, stream>>>(visA, WoT, nullptr, nullptr, out, 1);
}

// Round 5
// 277.207 us; speedup vs baseline: 1.6156x; 1.0332x over previous
//
#include <hip/hip_runtime.h>

typedef unsigned short u16;
typedef unsigned int u32;
typedef __bf16 bf16x8 __attribute__((ext_vector_type(8)));
typedef float f32x4 __attribute__((ext_vector_type(4)));
typedef u16 u16x4 __attribute__((ext_vector_type(4)));
typedef __attribute__((address_space(1))) void* as1_t;
typedef __attribute__((address_space(3))) void* as3_t;

#define LOG2E 1.4426950408889634f
#define MFMA(a,b,c) __builtin_amdgcn_mfma_f32_16x16x32_bf16(a,b,c,0,0,0)

__device__ __forceinline__ u16 f2bf(float f){
  u32 u = __float_as_uint(f);
  return (u16)((u + 0x7FFFu + ((u >> 16) & 1u)) >> 16);
}
__device__ __forceinline__ float bf2f(u16 x){
  return __uint_as_float(((u32)x) << 16);
}
#if __has_builtin(__builtin_amdgcn_cvt_pk_bf16_f32)
__device__ __forceinline__ u16x4 pk4(float a, float b, float c, float d){
  auto lo = __builtin_amdgcn_cvt_pk_bf16_f32(a,b);
  auto hi = __builtin_amdgcn_cvt_pk_bf16_f32(c,d);
  union { u16x4 v; u32 w[2]; } u;
  u.w[0] = __builtin_bit_cast(u32, lo);
  u.w[1] = __builtin_bit_cast(u32, hi);
  return u.v;
}
#else
__device__ __forceinline__ u16x4 pk4(float a, float b, float c, float d){
  u16x4 r = { f2bf(a), f2bf(b), f2bf(c), f2bf(d) };
  return r;
}
#endif
__device__ __forceinline__ void gld16(const u16* gp, u16* lp){
  __builtin_amdgcn_global_load_lds((as1_t)(u16*)gp, (as3_t)lp, 16, 0, 0);
}

// ---------------- prep: cast both inputs + all 5 weight transposes, ONE launch ----------------
// blocks [0,4096): cast vis; [4096,8192): cast txt; [8192,9472): 5 x 256 transpose tiles
__global__ void prep_kernel(const float* __restrict__ vis, u16* __restrict__ vis16,
                            const float* __restrict__ txt, u16* __restrict__ txt16,
                            const float* __restrict__ Wq, const float* __restrict__ Wk,
                            const float* __restrict__ Wv, const float* __restrict__ Wo,
                            u16* __restrict__ T0, u16* __restrict__ T1,
                            u16* __restrict__ T2, u16* __restrict__ T3,
                            u16* __restrict__ T4){
  int bid = blockIdx.x;
  if(bid < 8192){
    const float* src = (bid < 4096) ? vis : txt;
    u16* dst = (bid < 4096) ? vis16 : txt16;
    int idx = ((bid & 4095)*256 + threadIdx.x)*4;
    float4 v = *(const float4*)(src + idx);
    *(u16x4*)(dst + idx) = pk4(v.x, v.y, v.z, v.w);
    return;
  }
  int rr = bid - 8192;
  int wi = rr >> 8, tile = rr & 255;
  const float* W; u16* WT;
  switch(wi){
    case 0: W = Wq; WT = T0; break;
    case 1: W = Wv; WT = T1; break;
    case 2: W = Wk; WT = T2; break;
    case 3: W = Wv; WT = T3; break;
    default: W = Wo; WT = T4; break;
  }
  __shared__ u16 t[64][65];
  int bn = (tile & 15)*64, bk = (tile >> 4)*64;
  int c = threadIdx.x & 63, r0 = threadIdx.x >> 6;
  #pragma unroll
  for(int j=0;j<64;j+=4){
    int r = r0 + j;
    t[r][c] = f2bf(W[(bk + r)*1024 + bn + c]);
  }
  __syncthreads();
  #pragma unroll
  for(int j=0;j<64;j+=4){
    int r = r0 + j;
    WT[(bn + r)*1024 + bk + c] = t[c][r];
  }
}

// ---------------- merged projection GEMM, BK=64, z=0: vis->[Q | V2^T], z=1: txt->[K | V^T] --
// n<1024 -> Cn [b][h][s][d] (normal); n>=1024 -> Ct [b][h][d][s] (transposed, u16x4 stores)
__global__ __launch_bounds__(256, 2)
void proj_gemm_kernel(const u16* __restrict__ Avis, const u16* __restrict__ Atxt,
                      const u16* __restrict__ Wvis, const u16* __restrict__ Wtxt,
                      u16* __restrict__ Qb, u16* __restrict__ V2t,
                      u16* __restrict__ Kb, u16* __restrict__ Vt)
{
  const u16 *A, *Bt; u16 *Cn, *Ct;
  if(blockIdx.z == 0){ A = Avis; Bt = Wvis; Cn = Qb; Ct = V2t; }
  else               { A = Atxt; Bt = Wtxt; Cn = Kb; Ct = Vt;  }
  __shared__ u16 lds[16384];       // A: [c8][128][8], B: [c8][128][8]
  u16* Al = lds; u16* Bl = lds + 8192;
  const int tid = threadIdx.x, w = tid >> 6, lane = tid & 63;
  const int quad = lane >> 4, cl = lane & 15;
  const int bm = blockIdx.y*128, bn = blockIdx.x*128;
  const int wm = (w >> 1)*64, wn = (w & 1)*64;
  f32x4 acc[4][4];
  #pragma unroll
  for(int a=0;a<4;a++)
    #pragma unroll
    for(int b=0;b<4;b++){ f32x4 z = {0.f,0.f,0.f,0.f}; acc[a][b] = z; }

  for(int k0=0;k0<1024;k0+=64){
    __syncthreads();
    #pragma unroll
    for(int i=0;i<4;i++){
      int slot = (w*4+i)*64 + lane;
      int c = slot >> 7, r = slot & 127;
      gld16(A  + (size_t)(bm + r)*1024 + k0 + c*8, Al + (w*4+i)*512);
      gld16(Bt + (size_t)(bn + r)*1024 + k0 + c*8, Bl + (w*4+i)*512);
    }
    __syncthreads();
    bf16x8 af[4][2], bfv[4][2];
    #pragma unroll
    for(int mt=0;mt<4;mt++)
      #pragma unroll
      for(int kc=0;kc<2;kc++)
        af[mt][kc] = *(const bf16x8*)(Al + (((kc*4+quad)*128) + wm + mt*16 + cl)*8);
    #pragma unroll
    for(int nt=0;nt<4;nt++)
      #pragma unroll
      for(int kc=0;kc<2;kc++)
        bfv[nt][kc] = *(const bf16x8*)(Bl + (((kc*4+quad)*128) + wn + nt*16 + cl)*8);
    #pragma unroll
    for(int mt=0;mt<4;mt++)
      #pragma unroll
      for(int nt=0;nt<4;nt++)
        #pragma unroll
        for(int kc=0;kc<2;kc++)
          acc[mt][nt] = MFMA(af[mt][kc], bfv[nt][kc], acc[mt][nt]);
  }
  #pragma unroll
  for(int mt=0;mt<4;mt++)
    #pragma unroll
    for(int nt=0;nt<4;nt++){
      int n = bn + wn + nt*16 + cl;
      int m0 = bm + wm + mt*16 + quad*4;
      if(n < 1024){
        int h = n >> 6, d = n & 63;
        #pragma unroll
        for(int i=0;i<4;i++){
          int m = m0 + i;
          int b = m >> 10, s = m & 1023;
          Cn[(((size_t)(b*16 + h)*1024 + s) << 6) + d] = f2bf(acc[mt][nt][i]);
        }
      } else {
        int nn = n - 1024, h = nn >> 6, d = nn & 63;
        int b = m0 >> 10, s = m0 & 1023;
        *(u16x4*)(Ct + (((size_t)(b*16 + h)*64 + d) << 10) + s) =
            pk4(acc[mt][nt][0], acc[mt][nt][1], acc[mt][nt][2], acc[mt][nt][3]);
      }
    }
}

// ---------------- output GEMM: out[8192 x 1024] f32 = A[8192 x 1024] * WoT, BK=64 ----------------
__global__ __launch_bounds__(256, 2)
void out_gemm_kernel(const u16* __restrict__ A, const u16* __restrict__ Bt,
                     float* __restrict__ Cf)
{
  __shared__ u16 lds[16384];
  u16* Al = lds; u16* Bl = lds + 8192;
  const int tid = threadIdx.x, w = tid >> 6, lane = tid & 63;
  const int quad = lane >> 4, cl = lane & 15;
  const int bm = blockIdx.y*128, bn = blockIdx.x*128;
  const int wm = (w >> 1)*64, wn = (w & 1)*64;
  f32x4 acc[4][4];
  #pragma unroll
  for(int a=0;a<4;a++)
    #pragma unroll
    for(int b=0;b<4;b++){ f32x4 z = {0.f,0.f,0.f,0.f}; acc[a][b] = z; }

  for(int k0=0;k0<1024;k0+=64){
    __syncthreads();
    #pragma unroll
    for(int i=0;i<4;i++){
      int slot = (w*4+i)*64 + lane;
      int c = slot >> 7, r = slot & 127;
      gld16(A  + (size_t)(bm + r)*1024 + k0 + c*8, Al + (w*4+i)*512);
      gld16(Bt + (size_t)(bn + r)*1024 + k0 + c*8, Bl + (w*4+i)*512);
    }
    __syncthreads();
    bf16x8 af[4][2], bfv[4][2];
    #pragma unroll
    for(int mt=0;mt<4;mt++)
      #pragma unroll
      for(int kc=0;kc<2;kc++)
        af[mt][kc] = *(const bf16x8*)(Al + (((kc*4+quad)*128) + wm + mt*16 + cl)*8);
    #pragma unroll
    for(int nt=0;nt<4;nt++)
      #pragma unroll
      for(int kc=0;kc<2;kc++)
        bfv[nt][kc] = *(const bf16x8*)(Bl + (((kc*4+quad)*128) + wn + nt*16 + cl)*8);
    #pragma unroll
    for(int mt=0;mt<4;mt++)
      #pragma unroll
      for(int nt=0;nt<4;nt++)
        #pragma unroll
        for(int kc=0;kc<2;kc++)
          acc[mt][nt] = MFMA(af[mt][kc], bfv[nt][kc], acc[mt][nt]);
  }
  #pragma unroll
  for(int mt=0;mt<4;mt++)
    #pragma unroll
    for(int nt=0;nt<4;nt++)
      #pragma unroll
      for(int i=0;i<4;i++){
        int m = bm + wm + mt*16 + quad*4 + i;
        int n = bn + wn + nt*16 + cl;
        Cf[(size_t)m*1024 + n] = acc[mt][nt][i];
      }
}

// ---------------- attention (vis): 8 waves x 16 q-rows, no-max softmax, S^T tiles ----------------
__global__ __launch_bounds__(512, 4)
void attn_vis_kernel(const u16* __restrict__ Q, const u16* __restrict__ Kc,
                     const u16* __restrict__ Vt, u16* __restrict__ visA,
                     float* __restrict__ rl_g)
{
  __shared__ u16 lds[17408];   // 34816 B
  u16* Pl  = lds;              // P[q=128][72]; Q staged here first ([c8][128][8]=8192)
  u16* Kst = lds + 9216;       // [c8][64][8] = 4096 u16
  u16* Vst = lds + 13312;      // [d=64][ch^][8] swizzled = 4096 u16
  const int tid = threadIdx.x, w = tid>>6, lane = tid&63;
  const int quad = lane>>4, cl = lane&15;
  const int bh = blockIdx.y, q0 = blockIdx.x*128;
  const u16* Qh  = Q  + (size_t)bh*65536;
  const u16* Kh  = Kc + (size_t)bh*65536;
  const u16* Vth = Vt + (size_t)bh*65536;

  #pragma unroll
  for(int i=0;i<2;i++){
    int slot = i*512 + tid;
    int c = slot >> 7, r = slot & 127;
    gld16(Qh + (size_t)(q0 + r)*64 + c*8, Pl + slot*8);
  }
  __syncthreads();
  bf16x8 qf[2];
  #pragma unroll
  for(int kk=0;kk<2;kk++)
    qf[kk] = *(const bf16x8*)(Pl + ((kk*4+quad)*128 + w*16 + cl)*8);
  __syncthreads();   // Pl now becomes the P buffer

  float lrun = 0.f;
  f32x4 oacc[4];
  #pragma unroll
  for(int dt=0;dt<4;dt++){ f32x4 z = {0.f,0.f,0.f,0.f}; oacc[dt] = z; }

  for(int kt=0;kt<16;kt++){
    __syncthreads();
    {
      int slot = tid;
      { int c = slot >> 6, r = slot & 63;
        gld16(Kh + (size_t)(kt*64 + r)*64 + c*8, Kst + slot*8); }
      { int d = slot >> 3, ch = slot & 7;
        gld16(Vth + (size_t)d*1024 + kt*64 + (ch^(d&7))*8, Vst + slot*8); }
    }
    __syncthreads();
    #pragma unroll
    for(int mtk=0;mtk<4;mtk++){
      f32x4 s = {0.f,0.f,0.f,0.f};
      #pragma unroll
      for(int kk=0;kk<2;kk++){
        bf16x8 ka = *(const bf16x8*)(Kst + ((kk*4+quad)*64 + mtk*16 + cl)*8);
        s = MFMA(ka, qf[kk], s);
      }
      float p0 = __builtin_amdgcn_exp2f(s[0]*LOG2E);
      float p1 = __builtin_amdgcn_exp2f(s[1]*LOG2E);
      float p2 = __builtin_amdgcn_exp2f(s[2]*LOG2E);
      float p3 = __builtin_amdgcn_exp2f(s[3]*LOG2E);
      lrun += (p0+p1)+(p2+p3);
      *(u16x4*)(Pl + (w*16 + cl)*72 + mtk*16 + quad*4) = pk4(p0,p1,p2,p3);
    }
    bf16x8 pa[2];
    #pragma unroll
    for(int kk=0;kk<2;kk++)
      pa[kk] = *(const bf16x8*)(Pl + (w*16 + cl)*72 + kk*32 + quad*8);
    #pragma unroll
    for(int dt=0;dt<4;dt++){
      int d = dt*16 + cl;
      #pragma unroll
      for(int kk=0;kk<2;kk++){
        bf16x8 vb = *(const bf16x8*)(Vst + d*64 + (((kk*4+quad)^(d&7))*8));
        oacc[dt] = MFMA(pa[kk], vb, oacc[dt]);
      }
    }
  }
  lrun += __shfl_xor(lrun, 16, 64);
  lrun += __shfl_xor(lrun, 32, 64);
  float rl = 1.f/lrun;
  if(quad == 0) rl_g[bh*1024 + q0 + w*16 + cl] = rl;
  const int b = bh >> 4, h = bh & 15;
  #pragma unroll
  for(int i=0;i<4;i++){
    float rr = __shfl(rl, quad*4 + i, 16);
    int q = q0 + w*16 + quad*4 + i;
    #pragma unroll
    for(int dt=0;dt<4;dt++)
      visA[(size_t)(b*1024 + q)*1024 + h*64 + dt*16 + cl] = f2bf(oacc[dt][i]*rr);
  }
}

// ---------------- attention (txt): 8 waves x 16 k-rows; rl applied in-kernel ----------------
__global__ __launch_bounds__(512, 4)
void attn_txt_kernel(const u16* __restrict__ Kc, const u16* __restrict__ Q,
                     const u16* __restrict__ V2t, const float* __restrict__ rl_g,
                     u16* __restrict__ txtA)
{
  __shared__ u16 lds[17408];
  u16* Pl  = lds;              // P^T[k=128][72]; K-block staged here first
  u16* Qst = lds + 9216;       // [c8][64][8]
  u16* Vst = lds + 13312;      // [d][ch^][8] swizzled (contraction = q)
  const int tid = threadIdx.x, w = tid>>6, lane = tid&63;
  const int quad = lane>>4, cl = lane&15;
  const int bh = blockIdx.y, k0 = blockIdx.x*128;
  const u16* Kh  = Kc  + (size_t)bh*65536;
  const u16* Qh  = Q   + (size_t)bh*65536;
  const u16* Vth = V2t + (size_t)bh*65536;

  #pragma unroll
  for(int i=0;i<2;i++){
    int slot = i*512 + tid;
    int c = slot >> 7, r = slot & 127;
    gld16(Kh + (size_t)(k0 + r)*64 + c*8, Pl + slot*8);
  }
  __syncthreads();
  bf16x8 kb[2];
  #pragma unroll
  for(int kk=0;kk<2;kk++)
    kb[kk] = *(const bf16x8*)(Pl + ((kk*4+quad)*128 + w*16 + cl)*8);
  __syncthreads();

  f32x4 oacc[4];
  #pragma unroll
  for(int dt=0;dt<4;dt++){ f32x4 z = {0.f,0.f,0.f,0.f}; oacc[dt] = z; }

  for(int qt=0;qt<16;qt++){
    __syncthreads();
    {
      int slot = tid;
      { int c = slot >> 6, r = slot & 63;
        gld16(Qh + (size_t)(qt*64 + r)*64 + c*8, Qst + slot*8); }
      { int d = slot >> 3, ch = slot & 7;
        gld16(Vth + (size_t)d*1024 + qt*64 + (ch^(d&7))*8, Vst + slot*8); }
    }
    __syncthreads();
    f32x4 rv[4];
    #pragma unroll
    for(int mtq=0;mtq<4;mtq++)
      rv[mtq] = *(const f32x4*)(rl_g + bh*1024 + qt*64 + mtq*16 + quad*4);
    #pragma unroll
    for(int mtq=0;mtq<4;mtq++){
      f32x4 s = {0.f,0.f,0.f,0.f};
      #pragma unroll
      for(int kk=0;kk<2;kk++){
        bf16x8 qa = *(const bf16x8*)(Qst + ((kk*4+quad)*64 + mtq*16 + cl)*8);
        s = MFMA(qa, kb[kk], s);
      }
      float p0 = __builtin_amdgcn_exp2f(s[0]*LOG2E)*rv[mtq][0];
      float p1 = __builtin_amdgcn_exp2f(s[1]*LOG2E)*rv[mtq][1];
      float p2 = __builtin_amdgcn_exp2f(s[2]*LOG2E)*rv[mtq][2];
      float p3 = __builtin_amdgcn_exp2f(s[3]*LOG2E)*rv[mtq][3];
      *(u16x4*)(Pl + (w*16 + cl)*72 + mtq*16 + quad*4) = pk4(p0,p1,p2,p3);
    }
    bf16x8 pa[2];
    #pragma unroll
    for(int kk=0;kk<2;kk++)
      pa[kk] = *(const bf16x8*)(Pl + (w*16 + cl)*72 + kk*32 + quad*8);
    #pragma unroll
    for(int dt=0;dt<4;dt++){
      int d = dt*16 + cl;
      #pragma unroll
      for(int kk=0;kk<2;kk++){
        bf16x8 vb = *(const bf16x8*)(Vst + d*64 + (((kk*4+quad)^(d&7))*8));
        oacc[dt] = MFMA(pa[kk], vb, oacc[dt]);
      }
    }
  }
  const int b = bh >> 4, h = bh & 15;
  #pragma unroll
  for(int i=0;i<4;i++){
    int k = k0 + w*16 + quad*4 + i;
    #pragma unroll
    for(int dt=0;dt<4;dt++)
      txtA[(size_t)(b*1024 + k)*1024 + h*64 + dt*16 + cl] = f2bf(oacc[dt][i]);
  }
}

extern "C" void kernel_launch(void* const* d_in, const int* in_sizes, int n_in,
                              void* d_out, int out_size, void* d_ws, size_t ws_size,
                              hipStream_t stream)
{
  const float* vis = (const float*)d_in[0];
  const float* txt = (const float*)d_in[1];
  const float* Wq  = (const float*)d_in[2];
  const float* Wk  = (const float*)d_in[3];
  const float* Wv  = (const float*)d_in[4];
  const float* Wo  = (const float*)d_in[5];
  float* out = (float*)d_out;

  char* ws = (char*)d_ws;
  const size_t MB = 1u << 20;
  u16* vis16 = (u16*)(ws + 0);           // later: visA
  u16* txt16 = (u16*)(ws + 8*MB);        // later: txtA (contiguous with visA for out GEMM)
  u16* Wvis  = (u16*)(ws + 16*MB);       // [WqT | WvT]
  u16* Wtxt  = (u16*)(ws + 20*MB);       // [WkT | WvT]
  u16* Qb    = (u16*)(ws + 24*MB);
  u16* Kb    = (u16*)(ws + 32*MB);
  u16* Vt    = (u16*)(ws + 40*MB);       // V^T  [b][h][d][s]  (from txt proj)
  u16* V2t   = (u16*)(ws + 48*MB);       // V2^T [b][h][d][s]  (from vis proj)
  float* rl_g = (float*)(ws + 56*MB);
  u16* WoT   = (u16*)(ws + 57*MB);
  u16* visA = vis16;  u16* txtA = txt16;

  // 1: cast both inputs + 5 weight transposes
  prep_kernel<<<9472, 256, 0, stream>>>(vis, vis16, txt, txt16,
                                        Wq, Wk, Wv, Wo,
                                        Wvis, Wvis + 1048576, Wtxt, Wtxt + 1048576, WoT);
  // 2: merged projections; V/V2 written pre-transposed
  proj_gemm_kernel<<<dim3(16,32,2), 256, 0, stream>>>(vis16, txt16, Wvis, Wtxt,
                                                      Qb, V2t, Kb, Vt);
  // 3: attention vis (produces rl); visA overwrites vis16 (dead after projections)
  attn_vis_kernel<<<dim3(8,64), 512, 0, stream>>>(Qb, Kb, Vt, visA, rl_g);
  // 4: attention txt (applies rl in-kernel); txtA overwrites txt16
  attn_txt_kernel<<<dim3(8,64), 512, 0, stream>>>(Kb, Qb, V2t, rl_g, txtA);
  // 5: merged output projection: M=8192 over visA||txtA (contiguous), f32 out
  out_gemm_kernel<<<dim3(8,64), 256, 0, stream>>>(visA, WoT, out);
}

// Round 6
// 272.578 us; speedup vs baseline: 1.6431x; 1.0170x over previous
//
#include <hip/hip_runtime.h>

typedef unsigned short u16;
typedef unsigned int u32;
typedef __bf16 bf16x8 __attribute__((ext_vector_type(8)));
typedef float f32x4 __attribute__((ext_vector_type(4)));
typedef u16 u16x4 __attribute__((ext_vector_type(4)));
typedef __attribute__((address_space(1))) void* as1_t;
typedef __attribute__((address_space(3))) void* as3_t;

#define LOG2E 1.4426950408889634f
#define MFMA(a,b,c) __builtin_amdgcn_mfma_f32_16x16x32_bf16(a,b,c,0,0,0)

__device__ __forceinline__ u16 f2bf(float f){
  u32 u = __float_as_uint(f);
  return (u16)((u + 0x7FFFu + ((u >> 16) & 1u)) >> 16);
}
__device__ __forceinline__ float bf2f(u16 x){
  return __uint_as_float(((u32)x) << 16);
}
#if __has_builtin(__builtin_amdgcn_cvt_pk_bf16_f32)
__device__ __forceinline__ u16x4 pk4(float a, float b, float c, float d){
  auto lo = __builtin_amdgcn_cvt_pk_bf16_f32(a,b);
  auto hi = __builtin_amdgcn_cvt_pk_bf16_f32(c,d);
  union { u16x4 v; u32 w[2]; } u;
  u.w[0] = __builtin_bit_cast(u32, lo);
  u.w[1] = __builtin_bit_cast(u32, hi);
  return u.v;
}
#else
__device__ __forceinline__ u16x4 pk4(float a, float b, float c, float d){
  u16x4 r = { f2bf(a), f2bf(b), f2bf(c), f2bf(d) };
  return r;
}
#endif
__device__ __forceinline__ void gld16(const u16* gp, u16* lp){
  __builtin_amdgcn_global_load_lds((as1_t)(u16*)gp, (as3_t)lp, 16, 0, 0);
}

// ---------------- prep: cast both inputs + all 5 weight transposes, ONE launch ----------------
__global__ void prep_kernel(const float* __restrict__ vis, u16* __restrict__ vis16,
                            const float* __restrict__ txt, u16* __restrict__ txt16,
                            const float* __restrict__ Wq, const float* __restrict__ Wk,
                            const float* __restrict__ Wv, const float* __restrict__ Wo,
                            u16* __restrict__ T0, u16* __restrict__ T1,
                            u16* __restrict__ T2, u16* __restrict__ T3,
                            u16* __restrict__ T4){
  int bid = blockIdx.x;
  if(bid < 8192){
    const float* src = (bid < 4096) ? vis : txt;
    u16* dst = (bid < 4096) ? vis16 : txt16;
    int idx = ((bid & 4095)*256 + threadIdx.x)*4;
    float4 v = *(const float4*)(src + idx);
    *(u16x4*)(dst + idx) = pk4(v.x, v.y, v.z, v.w);
    return;
  }
  int rr = bid - 8192;
  int wi = rr >> 8, tile = rr & 255;
  const float* W; u16* WT;
  switch(wi){
    case 0: W = Wq; WT = T0; break;
    case 1: W = Wv; WT = T1; break;
    case 2: W = Wk; WT = T2; break;
    case 3: W = Wv; WT = T3; break;
    default: W = Wo; WT = T4; break;
  }
  __shared__ u16 t[64][65];
  int bn = (tile & 15)*64, bk = (tile >> 4)*64;
  int c = threadIdx.x & 63, r0 = threadIdx.x >> 6;
  #pragma unroll
  for(int j=0;j<64;j+=4){
    int r = r0 + j;
    t[r][c] = f2bf(W[(bk + r)*1024 + bn + c]);
  }
  __syncthreads();
  #pragma unroll
  for(int j=0;j<64;j+=4){
    int r = r0 + j;
    WT[(bn + r)*1024 + bk + c] = t[c][r];
  }
}

// ---------------- merged projection GEMM: 256x128 tile, 512 thr (8 waves of 64x64), BK=64 ----
// z=0: vis->[Q | V2^T], z=1: txt->[K | V^T]
// n<1024 -> Cn [b][h][s][d] (normal); n>=1024 -> Ct [b][h][d][s] (transposed, u16x4 stores)
__global__ __launch_bounds__(512, 2)
void proj_gemm_kernel(const u16* __restrict__ Avis, const u16* __restrict__ Atxt,
                      const u16* __restrict__ Wvis, const u16* __restrict__ Wtxt,
                      u16* __restrict__ Qb, u16* __restrict__ V2t,
                      u16* __restrict__ Kb, u16* __restrict__ Vt)
{
  const u16 *A, *Bt; u16 *Cn, *Ct;
  if(blockIdx.z == 0){ A = Avis; Bt = Wvis; Cn = Qb; Ct = V2t; }
  else               { A = Atxt; Bt = Wtxt; Cn = Kb; Ct = Vt;  }
  __shared__ u16 lds[24576];       // A: [c8][256][8] = 16384, B: [c8][128][8] = 8192
  u16* Al = lds; u16* Bl = lds + 16384;
  const int tid = threadIdx.x, w = tid >> 6, lane = tid & 63;
  const int quad = lane >> 4, cl = lane & 15;
  const int bm = blockIdx.y*256, bn = blockIdx.x*128;
  const int wm = (w & 3)*64, wn = (w >> 2)*64;
  f32x4 acc[4][4];
  #pragma unroll
  for(int a=0;a<4;a++)
    #pragma unroll
    for(int b=0;b<4;b++){ f32x4 z = {0.f,0.f,0.f,0.f}; acc[a][b] = z; }

  for(int k0=0;k0<1024;k0+=64){
    __syncthreads();
    #pragma unroll
    for(int i=0;i<4;i++){          // A-tile: 2048 slots
      int slot = i*512 + tid;
      int c = slot >> 8, r = slot & 255;
      gld16(A + (size_t)(bm + r)*1024 + k0 + c*8, Al + (i*512 + w*64)*8);
    }
    #pragma unroll
    for(int i=0;i<2;i++){          // B-tile: 1024 slots
      int slot = i*512 + tid;
      int c = slot >> 7, r = slot & 127;
      gld16(Bt + (size_t)(bn + r)*1024 + k0 + c*8, Bl + (i*512 + w*64)*8);
    }
    __syncthreads();
    bf16x8 af[4][2], bfv[4][2];
    #pragma unroll
    for(int mt=0;mt<4;mt++)
      #pragma unroll
      for(int kc=0;kc<2;kc++)
        af[mt][kc] = *(const bf16x8*)(Al + (((kc*4+quad)*256) + wm + mt*16 + cl)*8);
    #pragma unroll
    for(int nt=0;nt<4;nt++)
      #pragma unroll
      for(int kc=0;kc<2;kc++)
        bfv[nt][kc] = *(const bf16x8*)(Bl + (((kc*4+quad)*128) + wn + nt*16 + cl)*8);
    #pragma unroll
    for(int mt=0;mt<4;mt++)
      #pragma unroll
      for(int nt=0;nt<4;nt++)
        #pragma unroll
        for(int kc=0;kc<2;kc++)
          acc[mt][nt] = MFMA(af[mt][kc], bfv[nt][kc], acc[mt][nt]);
  }
  #pragma unroll
  for(int mt=0;mt<4;mt++)
    #pragma unroll
    for(int nt=0;nt<4;nt++){
      int n = bn + wn + nt*16 + cl;
      int m0 = bm + wm + mt*16 + quad*4;
      if(n < 1024){
        int h = n >> 6, d = n & 63;
        #pragma unroll
        for(int i=0;i<4;i++){
          int m = m0 + i;
          int b = m >> 10, s = m & 1023;
          Cn[(((size_t)(b*16 + h)*1024 + s) << 6) + d] = f2bf(acc[mt][nt][i]);
        }
      } else {
        int nn = n - 1024, h = nn >> 6, d = nn & 63;
        int b = m0 >> 10, s = m0 & 1023;
        *(u16x4*)(Ct + (((size_t)(b*16 + h)*64 + d) << 10) + s) =
            pk4(acc[mt][nt][0], acc[mt][nt][1], acc[mt][nt][2], acc[mt][nt][3]);
      }
    }
}

// ---------------- output GEMM: out[8192 x 1024] f32 = A[8192 x 1024] * WoT, BK=64 ----------------
__global__ __launch_bounds__(256, 2)
void out_gemm_kernel(const u16* __restrict__ A, const u16* __restrict__ Bt,
                     float* __restrict__ Cf)
{
  __shared__ u16 lds[16384];
  u16* Al = lds; u16* Bl = lds + 8192;
  const int tid = threadIdx.x, w = tid >> 6, lane = tid & 63;
  const int quad = lane >> 4, cl = lane & 15;
  const int bm = blockIdx.y*128, bn = blockIdx.x*128;
  const int wm = (w >> 1)*64, wn = (w & 1)*64;
  f32x4 acc[4][4];
  #pragma unroll
  for(int a=0;a<4;a++)
    #pragma unroll
    for(int b=0;b<4;b++){ f32x4 z = {0.f,0.f,0.f,0.f}; acc[a][b] = z; }

  for(int k0=0;k0<1024;k0+=64){
    __syncthreads();
    #pragma unroll
    for(int i=0;i<4;i++){
      int slot = (w*4+i)*64 + lane;
      int c = slot >> 7, r = slot & 127;
      gld16(A  + (size_t)(bm + r)*1024 + k0 + c*8, Al + (w*4+i)*512);
      gld16(Bt + (size_t)(bn + r)*1024 + k0 + c*8, Bl + (w*4+i)*512);
    }
    __syncthreads();
    bf16x8 af[4][2], bfv[4][2];
    #pragma unroll
    for(int mt=0;mt<4;mt++)
      #pragma unroll
      for(int kc=0;kc<2;kc++)
        af[mt][kc] = *(const bf16x8*)(Al + (((kc*4+quad)*128) + wm + mt*16 + cl)*8);
    #pragma unroll
    for(int nt=0;nt<4;nt++)
      #pragma unroll
      for(int kc=0;kc<2;kc++)
        bfv[nt][kc] = *(const bf16x8*)(Bl + (((kc*4+quad)*128) + wn + nt*16 + cl)*8);
    #pragma unroll
    for(int mt=0;mt<4;mt++)
      #pragma unroll
      for(int nt=0;nt<4;nt++)
        #pragma unroll
        for(int kc=0;kc<2;kc++)
          acc[mt][nt] = MFMA(af[mt][kc], bfv[nt][kc], acc[mt][nt]);
  }
  #pragma unroll
  for(int mt=0;mt<4;mt++)
    #pragma unroll
    for(int nt=0;nt<4;nt++)
      #pragma unroll
      for(int i=0;i<4;i++){
        int m = bm + wm + mt*16 + quad*4 + i;
        int n = bn + wn + nt*16 + cl;
        Cf[(size_t)m*1024 + n] = acc[mt][nt][i];
      }
}

// ---------------- attention (vis): 8 waves x 16 q-rows; grid x=bh (XCD-grouped K/V) ----------------
__global__ __launch_bounds__(512, 4)
void attn_vis_kernel(const u16* __restrict__ Q, const u16* __restrict__ Kc,
                     const u16* __restrict__ Vt, u16* __restrict__ visA,
                     float* __restrict__ rl_g)
{
  __shared__ u16 lds[17408];   // 34816 B
  u16* Pl  = lds;              // P[q=128][72]; Q staged here first ([c8][128][8]=8192)
  u16* Kst = lds + 9216;       // [c8][64][8] = 4096 u16
  u16* Vst = lds + 13312;      // [d=64][ch^][8] swizzled = 4096 u16
  const int tid = threadIdx.x, w = tid>>6, lane = tid&63;
  const int quad = lane>>4, cl = lane&15;
  const int bh = blockIdx.x, q0 = blockIdx.y*128;   // XCD = bh % 8
  const u16* Qh  = Q  + (size_t)bh*65536;
  const u16* Kh  = Kc + (size_t)bh*65536;
  const u16* Vth = Vt + (size_t)bh*65536;

  #pragma unroll
  for(int i=0;i<2;i++){
    int slot = i*512 + tid;
    int c = slot >> 7, r = slot & 127;
    gld16(Qh + (size_t)(q0 + r)*64 + c*8, Pl + slot*8);
  }
  __syncthreads();
  bf16x8 qf[2];
  #pragma unroll
  for(int kk=0;kk<2;kk++)
    qf[kk] = *(const bf16x8*)(Pl + ((kk*4+quad)*128 + w*16 + cl)*8);
  __syncthreads();   // Pl now becomes the P buffer

  float lrun = 0.f;
  f32x4 oacc[4];
  #pragma unroll
  for(int dt=0;dt<4;dt++){ f32x4 z = {0.f,0.f,0.f,0.f}; oacc[dt] = z; }

  for(int kt=0;kt<16;kt++){
    __syncthreads();
    {
      int slot = tid;
      { int c = slot >> 6, r = slot & 63;
        gld16(Kh + (size_t)(kt*64 + r)*64 + c*8, Kst + slot*8); }
      { int d = slot >> 3, ch = slot & 7;
        gld16(Vth + (size_t)d*1024 + kt*64 + (ch^(d&7))*8, Vst + slot*8); }
    }
    __syncthreads();
    #pragma unroll
    for(int mtk=0;mtk<4;mtk++){
      f32x4 s = {0.f,0.f,0.f,0.f};
      #pragma unroll
      for(int kk=0;kk<2;kk++){
        bf16x8 ka = *(const bf16x8*)(Kst + ((kk*4+quad)*64 + mtk*16 + cl)*8);
        s = MFMA(ka, qf[kk], s);
      }
      float p0 = __builtin_amdgcn_exp2f(s[0]*LOG2E);
      float p1 = __builtin_amdgcn_exp2f(s[1]*LOG2E);
      float p2 = __builtin_amdgcn_exp2f(s[2]*LOG2E);
      float p3 = __builtin_amdgcn_exp2f(s[3]*LOG2E);
      lrun += (p0+p1)+(p2+p3);
      *(u16x4*)(Pl + (w*16 + cl)*72 + mtk*16 + quad*4) = pk4(p0,p1,p2,p3);
    }
    bf16x8 pa[2];
    #pragma unroll
    for(int kk=0;kk<2;kk++)
      pa[kk] = *(const bf16x8*)(Pl + (w*16 + cl)*72 + kk*32 + quad*8);
    #pragma unroll
    for(int dt=0;dt<4;dt++){
      int d = dt*16 + cl;
      #pragma unroll
      for(int kk=0;kk<2;kk++){
        bf16x8 vb = *(const bf16x8*)(Vst + d*64 + (((kk*4+quad)^(d&7))*8));
        oacc[dt] = MFMA(pa[kk], vb, oacc[dt]);
      }
    }
  }
  lrun += __shfl_xor(lrun, 16, 64);
  lrun += __shfl_xor(lrun, 32, 64);
  float rl = 1.f/lrun;
  if(quad == 0) rl_g[bh*1024 + q0 + w*16 + cl] = rl;
  const int b = bh >> 4, h = bh & 15;
  #pragma unroll
  for(int i=0;i<4;i++){
    float rr = __shfl(rl, quad*4 + i, 16);
    int q = q0 + w*16 + quad*4 + i;
    #pragma unroll
    for(int dt=0;dt<4;dt++)
      visA[(size_t)(b*1024 + q)*1024 + h*64 + dt*16 + cl] = f2bf(oacc[dt][i]*rr);
  }
}

// ---------------- attention (txt): 8 waves x 16 k-rows; grid x=bh; rl applied in-kernel ----------
__global__ __launch_bounds__(512, 4)
void attn_txt_kernel(const u16* __restrict__ Kc, const u16* __restrict__ Q,
                     const u16* __restrict__ V2t, const float* __restrict__ rl_g,
                     u16* __restrict__ txtA)
{
  __shared__ u16 lds[17408];
  u16* Pl  = lds;              // P^T[k=128][72]; K-block staged here first
  u16* Qst = lds + 9216;       // [c8][64][8]
  u16* Vst = lds + 13312;      // [d][ch^][8] swizzled (contraction = q)
  const int tid = threadIdx.x, w = tid>>6, lane = tid&63;
  const int quad = lane>>4, cl = lane&15;
  const int bh = blockIdx.x, k0 = blockIdx.y*128;   // XCD = bh % 8
  const u16* Kh  = Kc  + (size_t)bh*65536;
  const u16* Qh  = Q   + (size_t)bh*65536;
  const u16* Vth = V2t + (size_t)bh*65536;

  #pragma unroll
  for(int i=0;i<2;i++){
    int slot = i*512 + tid;
    int c = slot >> 7, r = slot & 127;
    gld16(Kh + (size_t)(k0 + r)*64 + c*8, Pl + slot*8);
  }
  __syncthreads();
  bf16x8 kb[2];
  #pragma unroll
  for(int kk=0;kk<2;kk++)
    kb[kk] = *(const bf16x8*)(Pl + ((kk*4+quad)*128 + w*16 + cl)*8);
  __syncthreads();

  f32x4 oacc[4];
  #pragma unroll
  for(int dt=0;dt<4;dt++){ f32x4 z = {0.f,0.f,0.f,0.f}; oacc[dt] = z; }

  for(int qt=0;qt<16;qt++){
    __syncthreads();
    {
      int slot = tid;
      { int c = slot >> 6, r = slot & 63;
        gld16(Qh + (size_t)(qt*64 + r)*64 + c*8, Qst + slot*8); }
      { int d = slot >> 3, ch = slot & 7;
        gld16(Vth + (size_t)d*1024 + qt*64 + (ch^(d&7))*8, Vst + slot*8); }
    }
    __syncthreads();
    f32x4 rv[4];
    #pragma unroll
    for(int mtq=0;mtq<4;mtq++)
      rv[mtq] = *(const f32x4*)(rl_g + bh*1024 + qt*64 + mtq*16 + quad*4);
    #pragma unroll
    for(int mtq=0;mtq<4;mtq++){
      f32x4 s = {0.f,0.f,0.f,0.f};
      #pragma unroll
      for(int kk=0;kk<2;kk++){
        bf16x8 qa = *(const bf16x8*)(Qst + ((kk*4+quad)*64 + mtq*16 + cl)*8);
        s = MFMA(qa, kb[kk], s);
      }
      float p0 = __builtin_amdgcn_exp2f(s[0]*LOG2E)*rv[mtq][0];
      float p1 = __builtin_amdgcn_exp2f(s[1]*LOG2E)*rv[mtq][1];
      float p2 = __builtin_amdgcn_exp2f(s[2]*LOG2E)*rv[mtq][2];
      float p3 = __builtin_amdgcn_exp2f(s[3]*LOG2E)*rv[mtq][3];
      *(u16x4*)(Pl + (w*16 + cl)*72 + mtq*16 + quad*4) = pk4(p0,p1,p2,p3);
    }
    bf16x8 pa[2];
    #pragma unroll
    for(int kk=0;kk<2;kk++)
      pa[kk] = *(const bf16x8*)(Pl + (w*16 + cl)*72 + kk*32 + quad*8);
    #pragma unroll
    for(int dt=0;dt<4;dt++){
      int d = dt*16 + cl;
      #pragma unroll
      for(int kk=0;kk<2;kk++){
        bf16x8 vb = *(const bf16x8*)(Vst + d*64 + (((kk*4+quad)^(d&7))*8));
        oacc[dt] = MFMA(pa[kk], vb, oacc[dt]);
      }
    }
  }
  const int b = bh >> 4, h = bh & 15;
  #pragma unroll
  for(int i=0;i<4;i++){
    int k = k0 + w*16 + quad*4 + i;
    #pragma unroll
    for(int dt=0;dt<4;dt++)
      txtA[(size_t)(b*1024 + k)*1024 + h*64 + dt*16 + cl] = f2bf(oacc[dt][i]);
  }
}

extern "C" void kernel_launch(void* const* d_in, const int* in_sizes, int n_in,
                              void* d_out, int out_size, void* d_ws, size_t ws_size,
                              hipStream_t stream)
{
  const float* vis = (const float*)d_in[0];
  const float* txt = (const float*)d_in[1];
  const float* Wq  = (const float*)d_in[2];
  const float* Wk  = (const float*)d_in[3];
  const float* Wv  = (const float*)d_in[4];
  const float* Wo  = (const float*)d_in[5];
  float* out = (float*)d_out;

  char* ws = (char*)d_ws;
  const size_t MB = 1u << 20;
  u16* vis16 = (u16*)(ws + 0);           // later: visA
  u16* txt16 = (u16*)(ws + 8*MB);        // later: txtA (contiguous with visA for out GEMM)
  u16* Wvis  = (u16*)(ws + 16*MB);       // [WqT | WvT]
  u16* Wtxt  = (u16*)(ws + 20*MB);       // [WkT | WvT]
  u16* Qb    = (u16*)(ws + 24*MB);
  u16* Kb    = (u16*)(ws + 32*MB);
  u16* Vt    = (u16*)(ws + 40*MB);       // V^T  [b][h][d][s]  (from txt proj)
  u16* V2t   = (u16*)(ws + 48*MB);       // V2^T [b][h][d][s]  (from vis proj)
  float* rl_g = (float*)(ws + 56*MB);
  u16* WoT   = (u16*)(ws + 57*MB);
  u16* visA = vis16;  u16* txtA = txt16;

  // 1: cast both inputs + 5 weight transposes
  prep_kernel<<<9472, 256, 0, stream>>>(vis, vis16, txt, txt16,
                                        Wq, Wk, Wv, Wo,
                                        Wvis, Wvis + 1048576, Wtxt, Wtxt + 1048576, WoT);
  // 2: merged projections, 256x128 tiles; V/V2 written pre-transposed
  proj_gemm_kernel<<<dim3(16,16,2), 512, 0, stream>>>(vis16, txt16, Wvis, Wtxt,
                                                      Qb, V2t, Kb, Vt);
  // 3: attention vis (produces rl); visA overwrites vis16 (dead after projections)
  attn_vis_kernel<<<dim3(64,8), 512, 0, stream>>>(Qb, Kb, Vt, visA, rl_g);
  // 4: attention txt (applies rl in-kernel); txtA overwrites txt16
  attn_txt_kernel<<<dim3(64,8), 512, 0, stream>>>(Kb, Qb, V2t, rl_g, txtA);
  // 5: merged output projection: M=8192 over visA||txtA (contiguous), f32 out
  out_gemm_kernel<<<dim3(8,64), 256, 0, stream>>>(visA, WoT, out);
}